// Round 3
// baseline (716.946 us; speedup 1.0000x reference)
//
#include <hip/hip_runtime.h>
#include <cstdint>
#include <cstddef>

#define BB 8
#define NQ 2048
#define NK 2048
#define DM 64
#define QT 8
#define AST 260          // padded LDS stride for attn stage (bank-conflict-free)
#define NEGC (-1e9f)

__device__ __forceinline__ float frcp(float x){
  float r = __builtin_amdgcn_rcpf(x);
  return r * (2.0f - x*r);   // one Newton step, ~1e-7 rel
}
__device__ __forceinline__ float softplus(float v){
  return fmaxf(v, 0.0f) + log1pf(__expf(-fabsf(v)));
}
__device__ __forceinline__ float wave_sum(float v){
  #pragma unroll
  for (int o = 32; o; o >>= 1) v += __shfl_down(v, o);
  return v;
}

// digamma + gammaln for x >= 1 (shift-to-8 + Stirling). abs err < 1e-6.
__device__ __forceinline__ void psi_lgam(float x, float& psi, float& lg){
  float xs = x, csum = 0.0f, prod = 1.0f;
  if (__any(xs < 8.0f)){
    #pragma unroll
    for (int s = 0; s < 7; ++s){
      if (xs < 8.0f){ csum += frcp(xs); prod *= xs; xs += 1.0f; }
    }
  }
  float rx  = frcp(xs);
  float lx  = __logf(xs);
  float rx2 = rx*rx;
  psi = lx - 0.5f*rx
      - rx2*(0.0833333333333f - rx2*(0.00833333333333f - rx2*0.00396825396825f))
      - csum;
  lg  = (xs - 0.5f)*lx - xs + 0.91893853320467274f
      + rx*(0.0833333333333f - rx2*(0.00277777777778f - rx2*0.000793650793651f));
  if (__any(prod != 1.0f)) lg -= __logf(prod);
}

// ---------------- Kernel A: fused 3-layer MLPs (q, k, va) ----------------
__global__ __launch_bounds__(256) void mlp3_kernel(
    const float* __restrict__ y, const float* __restrict__ x,
    const float* __restrict__ Wq, const float* __restrict__ bq,
    const float* __restrict__ Wk, const float* __restrict__ bk,
    const float* __restrict__ Wv, const float* __restrict__ bv,
    float* __restrict__ qo, float* __restrict__ ko, float* __restrict__ vo){
  const int which = blockIdx.y;                 // 0:q 1:k 2:va
  const float* src = (which == 0) ? y : x;
  const float* W   = (which == 0) ? Wq : (which == 1 ? Wk : Wv);
  const float* bb  = (which == 0) ? bq : (which == 1 ? bk : bv);
  float* dst       = (which == 0) ? qo : (which == 1 ? ko : vo);
  const bool last_sp = (which != 2);
  const int row0 = blockIdx.x * 4;
  const int r = threadIdx.x >> 6, c = threadIdx.x & 63;

  __shared__ float h[2][4][DM];
  __shared__ float Wl[DM][DM];

  h[0][r][c] = src[(size_t)(row0 + r)*DM + c];
  float acc = 0.0f;
  for (int l = 0; l < 3; ++l){
    __syncthreads();
    #pragma unroll
    for (int i = 0; i < 16; ++i)
      ((float*)Wl)[i*256 + threadIdx.x] = W[l*DM*DM + i*256 + threadIdx.x];
    __syncthreads();
    float wcol[DM];
    #pragma unroll
    for (int d = 0; d < DM; ++d) wcol[d] = Wl[d][c];
    acc = bb[l*DM + c];
    const float* hr = h[l & 1][r];
    #pragma unroll
    for (int d = 0; d < DM; ++d) acc = fmaf(hr[d], wcol[d], acc);
    if (l < 2 || last_sp) acc = softplus(acc);
    __syncthreads();
    h[(l + 1) & 1][r][c] = acc;
  }
  dst[(size_t)(row0 + r)*DM + c] = acc;
}

// ---------------- Kernel A2: transpose k -> kT[B][DM][NK] ----------------
__global__ __launch_bounds__(256) void ktrans_kernel(
    const float* __restrict__ k, float* __restrict__ kT){
  const int b = blockIdx.y, tile = blockIdx.x;  // tile of 64 rows
  const int t = threadIdx.x;
  __shared__ float ld[64][65];
  const float* src = k + (size_t)b*NK*DM + (size_t)tile*64*DM;
  #pragma unroll
  for (int p = 0; p < 4; ++p){
    int idx = t + p*256;                 // float4 index 0..1023
    int row = idx >> 4, c4 = idx & 15;
    float4 v = ((const float4*)src)[idx];
    ld[row][c4*4+0] = v.x; ld[row][c4*4+1] = v.y;
    ld[row][c4*4+2] = v.z; ld[row][c4*4+3] = v.w;
  }
  __syncthreads();
  float* dst = kT + (size_t)b*DM*NK + (size_t)tile*64;
  #pragma unroll
  for (int p = 0; p < 4; ++p){
    int idx = t + p*256;
    int d = idx >> 4, j4 = idx & 15;
    float4 v = { ld[j4*4+0][d], ld[j4*4+1][d], ld[j4*4+2][d], ld[j4*4+3][d] };
    ((float4*)(dst + (size_t)d*NK))[j4] = v;
  }
}

// ---------------- Kernel B: main fused attention ----------------
// 1-D grid, wg = b + 8*qtile (XCD-friendly). Thread t owns k-indices
// j = i*256+t (i=0..7); alpha/z kept in 64 registers.
// waves_per_eu(4,4): pin 4 waves/EU so the allocator uses up to 128 VGPR
// instead of shrinking to 64 and spilling z[64] to scratch (round-2 failure).
__attribute__((amdgpu_flat_work_group_size(256,256), amdgpu_waves_per_eu(4,4)))
__global__ void bayes_main_kernel(
    const float* __restrict__ qg, const float* __restrict__ kTg, const float* __restrict__ vag,
    const float* __restrict__ maskg, const float* __restrict__ epsg,
    float* __restrict__ outg, float* __restrict__ attng, float* __restrict__ klws){
  const int b  = blockIdx.x & 7;
  const int qt = blockIdx.x >> 3;
  const int q0 = qt * QT;
  const int t  = threadIdx.x;
  const int lane = t & 63, wid = t >> 6;

  __shared__ float4 qlds[QT][16];        // q tile (8 rows x 64)
  __shared__ float  aldsf[QT*AST];       // attn chunk stage, padded stride
  __shared__ float  wr6[4][QT][6];       // per-wave reduction slots
  __shared__ float  rowc1[QT], rowS2[QT], rowinv[QT], klrow[QT];

  if (t < 128)
    qlds[t >> 4][t & 15] = ((const float4*)qg)[(size_t)(b*NQ + q0)*16 + t];
  __syncthreads();

  // ---- pass A: qk dots via coalesced kT streams, z = alpha ----
  float z[QT][8];
  #pragma unroll
  for (int r = 0; r < QT; ++r)
    #pragma unroll
    for (int i = 0; i < 8; ++i) z[r][i] = 1.0f;   // alpha = qk + 1

  const float* kTb = kTg + (size_t)b*DM*NK;
  #pragma unroll 1
  for (int dblk = 0; dblk < 16; ++dblk){
    float4 qv[QT];
    #pragma unroll
    for (int r = 0; r < QT; ++r) qv[r] = qlds[r][dblk];
    const float* kc0 = kTb + (size_t)(dblk*4)*NK + t;
    #pragma unroll
    for (int i = 0; i < 8; ++i){
      float k0 = kc0[i*256];
      float k1 = kc0[i*256 + NK];
      float k2 = kc0[i*256 + 2*NK];
      float k3 = kc0[i*256 + 3*NK];
      #pragma unroll
      for (int r = 0; r < QT; ++r){
        float a = z[r][i];
        a = fmaf(k0, qv[r].x, a);
        a = fmaf(k1, qv[r].y, a);
        a = fmaf(k2, qv[r].z, a);
        a = fmaf(k3, qv[r].w, a);
        z[r][i] = a;
      }
    }
  }

  // ---- sweep 1: mask read, dirichlet sums ----
  unsigned mb[QT];
  #pragma unroll
  for (int r = 0; r < QT; ++r){
    float a0 = 0, Sg = 0, Sadg = 0, Sdg = 0, Sinv = 0, lat = 0;
    unsigned bits = 0;
    const float* mrow = maskg + ((size_t)(b*NQ) + q0 + r)*NK;
    #pragma unroll
    for (int i = 0; i < 8; ++i){
      float m = __builtin_nontemporal_load(mrow + i*256 + t);
      float a = z[r][i];
      if (m != 0.0f) bits |= (1u << i);
      float psi, lg;
      psi_lgam(a, psi, lg);
      float inv = frcp(a);
      a0   = fmaf(a,      m, a0);
      Sg   = fmaf(lg,     m, Sg);
      Sadg = fmaf(a*psi,  m, Sadg);
      Sdg  = fmaf(psi,    m, Sdg);
      Sinv = fmaf(inv,    m, Sinv);
      lat += m;
    }
    mb[r] = bits;
    a0 = wave_sum(a0); Sg = wave_sum(Sg); Sadg = wave_sum(Sadg);
    Sdg = wave_sum(Sdg); Sinv = wave_sum(Sinv); lat = wave_sum(lat);
    if (lane == 0){
      wr6[wid][r][0] = a0;  wr6[wid][r][1] = Sg;  wr6[wid][r][2] = Sadg;
      wr6[wid][r][3] = Sdg; wr6[wid][r][4] = Sinv; wr6[wid][r][5] = lat;
    }
  }
  __syncthreads();
  if (t < QT){
    const int r = t;
    float A0 = 0, SG = 0, SADG = 0, SDG = 0, SINV = 0, LT = 0;
    #pragma unroll
    for (int w = 0; w < 4; ++w){
      A0 += wr6[w][r][0]; SG += wr6[w][r][1]; SADG += wr6[w][r][2];
      SDG += wr6[w][r][3]; SINV += wr6[w][r][4]; LT += wr6[w][r][5];
    }
    float invLT = frcp(LT);
    rowc1[r] = 1.0f - 2.0f*invLT;
    rowS2[r] = SINV*invLT*invLT;
    // KLD combine in fp64 (cancellation of ~4e5-size terms down to ~1e3)
    double A0d = (double)A0, csum = 0.0, prod = 1.0;
    #pragma unroll
    for (int s = 0; s < 7; ++s){
      if (A0d < 8.0){ csum += 1.0/A0d; prod *= A0d; A0d += 1.0; }
    }
    double lx = log(A0d), r1 = 1.0/A0d, r2 = r1*r1;
    double psiA = lx - 0.5*r1
                - r2*((1.0/12.0) - r2*((1.0/120.0) - r2*(1.0/252.0))) - csum;
    double lgA  = (A0d - 0.5)*lx - A0d + 0.918938533204672741
                + r1*((1.0/12.0) - r2*((1.0/360.0) - r2*(1.0/1260.0))) - log(prod);
    double kl = lgA - (double)SG + (double)SADG - psiA*(double)A0
              - ((double)SDG - psiA*(double)LT)*(1.0/(double)NK);
    klrow[r] = (float)fabs(kl);
  }
  __syncthreads();
  if (t == 0){
    float s = 0;
    #pragma unroll
    for (int r = 0; r < QT; ++r) s += klrow[r];
    klws[b*(NQ/QT) + qt] = s;
  }

  // ---- sweep 2 (fused): z = exp(log a + sigma*eps), row sum.
  // No max-subtraction: alpha>=1 so log a in [0,~7], sigma*eps bounded (~|e|),
  // exp args <= ~20 — fp32-safe; softmax is shift-invariant.
  #pragma unroll
  for (int r = 0; r < QT; ++r){
    const float c1 = rowc1[r], S2 = rowS2[r];
    const float* erow = epsg + ((size_t)(b*NQ) + q0 + r)*NK;
    float s = 0.0f;
    #pragma unroll
    for (int i = 0; i < 8; ++i){
      float e = __builtin_nontemporal_load(erow + i*256 + t);
      float a = z[r][i];
      float e2;
      if ((mb[r] >> i) & 1u){
        float la = __logf(a);
        float zz = fmaf(fmaf(c1, frcp(a), S2), e, la);
        e2 = __expf(zz);
      } else {
        e2 = 0.0f;
      }
      z[r][i] = e2;
      s += e2;
    }
    s = wave_sum(s);
    if (lane == 0) wr6[wid][r][0] = s;
  }
  __syncthreads();
  if (t < QT)
    rowinv[t] = frcp(wr6[0][t][0] + wr6[1][t][0] + wr6[2][t][0] + wr6[3][t][0]);
  __syncthreads();

  float rinv[QT];
  #pragma unroll
  for (int r = 0; r < QT; ++r) rinv[r] = rowinv[r];

  // ---- sweep 3: write attn + out = attn @ va (float4 over d) ----
  const float* vb = vag + (size_t)b*NK*DM;
  const int d4 = t & 15;          // float4 column group
  const int rr = (t >> 4) & 7;    // q-row
  const int jh = t >> 7;          // j-half (0/1)
  float4 acc = {0.0f, 0.0f, 0.0f, 0.0f};
  #pragma unroll
  for (int i = 0; i < 8; ++i){
    #pragma unroll
    for (int r = 0; r < QT; ++r){
      float av = z[r][i] * rinv[r];
      __builtin_nontemporal_store(av, attng + ((size_t)(b*NQ) + q0 + r)*NK + i*256 + t);
      aldsf[r*AST + t] = av;
    }
    __syncthreads();
    const float* vchunk = vb + (size_t)(i*256)*DM + d4*4;
    #pragma unroll 4
    for (int j4 = 0; j4 < 32; ++j4){
      int j = jh*128 + j4*4;
      float4 a4 = *(const float4*)&aldsf[rr*AST + j];   // ds_read_b128, banks disjoint per rr
      float4 v0 = *(const float4*)(vchunk + (size_t)(j + 0)*DM);
      float4 v1 = *(const float4*)(vchunk + (size_t)(j + 1)*DM);
      float4 v2 = *(const float4*)(vchunk + (size_t)(j + 2)*DM);
      float4 v3 = *(const float4*)(vchunk + (size_t)(j + 3)*DM);
      acc.x = fmaf(a4.x, v0.x, fmaf(a4.y, v1.x, fmaf(a4.z, v2.x, fmaf(a4.w, v3.x, acc.x))));
      acc.y = fmaf(a4.x, v0.y, fmaf(a4.y, v1.y, fmaf(a4.z, v2.y, fmaf(a4.w, v3.y, acc.y))));
      acc.z = fmaf(a4.x, v0.z, fmaf(a4.y, v1.z, fmaf(a4.z, v2.z, fmaf(a4.w, v3.z, acc.z))));
      acc.w = fmaf(a4.x, v0.w, fmaf(a4.y, v1.w, fmaf(a4.z, v2.w, fmaf(a4.w, v3.w, acc.w))));
    }
    __syncthreads();
  }
  // combine the two j-halves
  if (jh == 1) *(float4*)&aldsf[(t - 128)*4] = acc;
  __syncthreads();
  if (jh == 0){
    float4 o = *(float4*)&aldsf[t*4];
    acc.x += o.x; acc.y += o.y; acc.z += o.z; acc.w += o.w;
    *(float4*)(outg + ((size_t)(b*NQ) + q0 + rr)*DM + d4*4) = acc;
  }
}

// ---------------- Kernel C: deterministic KLD reduce ----------------
__global__ __launch_bounds__(256) void kld_reduce_kernel(
    const float* __restrict__ klws, float* __restrict__ dst){
  float s = 0.0f;
  for (int i = threadIdx.x; i < BB*(NQ/QT); i += 256) s += klws[i];
  s = wave_sum(s);
  __shared__ float w4[4];
  if ((threadIdx.x & 63) == 0) w4[threadIdx.x >> 6] = s;
  __syncthreads();
  if (threadIdx.x == 0)
    dst[0] = (w4[0] + w4[1] + w4[2] + w4[3]) * (1.0f/((float)BB*(float)NQ));
}

extern "C" void kernel_launch(void* const* d_in, const int* in_sizes, int n_in,
                              void* d_out, int out_size, void* d_ws, size_t ws_size,
                              hipStream_t stream){
  const float* y    = (const float*)d_in[0];
  const float* x    = (const float*)d_in[1];
  const float* mask = (const float*)d_in[2];
  const float* eps  = (const float*)d_in[3];
  const float* Wq   = (const float*)d_in[4];
  const float* bq   = (const float*)d_in[5];
  const float* Wk   = (const float*)d_in[6];
  const float* bk   = (const float*)d_in[7];
  const float* Wv   = (const float*)d_in[8];
  const float* bv   = (const float*)d_in[9];

  float* out  = (float*)d_out;                       // [B,NQ,DM]
  float* attn = out  + (size_t)BB*NQ*DM;             // [B,NQ,NK]
  float* va   = attn + (size_t)BB*NQ*NK;             // [B,NK,DM]
  float* kld  = va   + (size_t)BB*NK*DM;             // [1]

  float* qws  = (float*)d_ws;                        // 4 MB
  float* kws  = qws  + (size_t)BB*NQ*DM;             // 4 MB
  float* kTws = kws  + (size_t)BB*NK*DM;             // 4 MB
  float* klws = kTws + (size_t)BB*DM*NK;             // 8 KB

  dim3 gA((BB*NQ)/4, 3);
  hipLaunchKernelGGL(mlp3_kernel, gA, dim3(256), 0, stream,
                     y, x, Wq, bq, Wk, bk, Wv, bv, qws, kws, va);
  hipLaunchKernelGGL(ktrans_kernel, dim3(NK/64, BB), dim3(256), 0, stream, kws, kTws);
  hipLaunchKernelGGL(bayes_main_kernel, dim3(BB*(NQ/QT)), dim3(256), 0, stream,
                     qws, kTws, va, mask, eps, out, attn, klws);
  hipLaunchKernelGGL(kld_reduce_kernel, dim3(1), dim3(256), 0, stream, klws, kld);
}

// Round 4
// 441.529 us; speedup vs baseline: 1.6238x; 1.6238x over previous
//
#include <hip/hip_runtime.h>
#include <cstdint>
#include <cstddef>

#define BB 8
#define NQ 2048
#define NK 2048
#define DM 64
#define QT 8
#define TPB 512
#define NEGC (-1e9f)

typedef float    f4   __attribute__((ext_vector_type(4)));
typedef unsigned u32x2 __attribute__((ext_vector_type(2)));
typedef unsigned u32x4 __attribute__((ext_vector_type(4)));

__device__ __forceinline__ float frcp(float x){
  float r = __builtin_amdgcn_rcpf(x);
  return r * (2.0f - x*r);
}
__device__ __forceinline__ float softplus(float v){
  return fmaxf(v, 0.0f) + log1pf(__expf(-fabsf(v)));
}
__device__ __forceinline__ float wave_sum(float v){
  #pragma unroll
  for (int o = 32; o; o >>= 1) v += __shfl_down(v, o);
  return v;
}
__device__ __forceinline__ float bflo(unsigned u){ return __uint_as_float(u << 16); }
__device__ __forceinline__ float bfhi(unsigned u){ return __uint_as_float(u & 0xffff0000u); }
// pack two f32 -> 2 bf16 (truncation; max 0.39% rel err, under 2% threshold)
__device__ __forceinline__ unsigned packtr(float lo, float hi){
  return (__float_as_uint(lo) >> 16) | (__float_as_uint(hi) & 0xffff0000u);
}
// f32 -> bf16 with round-to-nearest-even
__device__ __forceinline__ unsigned short f2bf(float f){
  unsigned u = __float_as_uint(f);
  return (unsigned short)((u + 0x7fffu + ((u >> 16) & 1u)) >> 16);
}
__device__ __forceinline__ unsigned pack_rne(float lo, float hi){
  return (unsigned)f2bf(lo) | ((unsigned)f2bf(hi) << 16);
}

// digamma + gammaln for x >= 1 (shift-to-8 + Stirling). abs err < 1e-6.
__device__ __forceinline__ void psi_lgam(float x, float& psi, float& lg){
  float xs = x, csum = 0.0f, prod = 1.0f;
  if (__any(xs < 8.0f)){
    #pragma unroll
    for (int s = 0; s < 7; ++s){
      if (xs < 8.0f){ csum += frcp(xs); prod *= xs; xs += 1.0f; }
    }
  }
  float rx  = frcp(xs);
  float lx  = __logf(xs);
  float rx2 = rx*rx;
  psi = lx - 0.5f*rx
      - rx2*(0.0833333333333f - rx2*(0.00833333333333f - rx2*0.00396825396825f))
      - csum;
  lg  = (xs - 0.5f)*lx - xs + 0.91893853320467274f
      + rx*(0.0833333333333f - rx2*(0.00277777777778f - rx2*0.000793650793651f));
  if (__any(prod != 1.0f)) lg -= __logf(prod);
}

// ---------------- Kernel A: fused 3-layer MLPs (q, k, va) ----------------
__global__ __launch_bounds__(256) void mlp3_kernel(
    const float* __restrict__ y, const float* __restrict__ x,
    const float* __restrict__ Wq, const float* __restrict__ bq,
    const float* __restrict__ Wk, const float* __restrict__ bk,
    const float* __restrict__ Wv, const float* __restrict__ bv,
    float* __restrict__ qo, float* __restrict__ ko, float* __restrict__ vo,
    unsigned short* __restrict__ vob){
  const int which = blockIdx.y;                 // 0:q 1:k 2:va
  const float* src = (which == 0) ? y : x;
  const float* W   = (which == 0) ? Wq : (which == 1 ? Wk : Wv);
  const float* bb  = (which == 0) ? bq : (which == 1 ? bk : bv);
  const bool last_sp = (which != 2);
  const int row0 = blockIdx.x * 4;
  const int r = threadIdx.x >> 6, c = threadIdx.x & 63;

  __shared__ float h[2][4][DM];
  __shared__ float Wl[DM][DM];

  h[0][r][c] = src[(size_t)(row0 + r)*DM + c];
  float acc = 0.0f;
  for (int l = 0; l < 3; ++l){
    __syncthreads();
    #pragma unroll
    for (int i = 0; i < 16; ++i)
      ((float*)Wl)[i*256 + threadIdx.x] = W[l*DM*DM + i*256 + threadIdx.x];
    __syncthreads();
    float wcol[DM];
    #pragma unroll
    for (int d = 0; d < DM; ++d) wcol[d] = Wl[d][c];
    acc = bb[l*DM + c];
    const float* hr = h[l & 1][r];
    #pragma unroll
    for (int d = 0; d < DM; ++d) acc = fmaf(hr[d], wcol[d], acc);
    if (l < 2 || last_sp) acc = softplus(acc);
    __syncthreads();
    h[(l + 1) & 1][r][c] = acc;
  }
  const size_t idx = (size_t)(row0 + r)*DM + c;
  if (which == 0)      qo[idx] = acc;
  else if (which == 1) ko[idx] = acc;
  else { vo[idx] = acc; vob[idx] = f2bf(acc); }
}

// ---------------- Kernel A2: transpose k -> kT[B][DM][NK] (bf16) ----------------
__global__ __launch_bounds__(256) void ktrans_kernel(
    const float* __restrict__ k, unsigned short* __restrict__ kT){
  const int b = blockIdx.y, tile = blockIdx.x;  // tile of 64 rows
  const int t = threadIdx.x;
  __shared__ float ld[64][65];
  const float* src = k + (size_t)b*NK*DM + (size_t)tile*64*DM;
  #pragma unroll
  for (int p = 0; p < 4; ++p){
    int idx = t + p*256;                 // float4 index 0..1023
    int row = idx >> 4, c4 = idx & 15;
    f4 v = ((const f4*)src)[idx];
    ld[row][c4*4+0] = v.x; ld[row][c4*4+1] = v.y;
    ld[row][c4*4+2] = v.z; ld[row][c4*4+3] = v.w;
  }
  __syncthreads();
  unsigned short* dst = kT + (size_t)b*DM*NK + (size_t)tile*64;
  #pragma unroll
  for (int p = 0; p < 4; ++p){
    int idx = t + p*256;
    int d = idx >> 4, j4 = idx & 15;
    u32x2 o = { pack_rne(ld[j4*4+0][d], ld[j4*4+1][d]),
                pack_rne(ld[j4*4+2][d], ld[j4*4+3][d]) };
    *(u32x2*)(dst + (size_t)d*NK + j4*4) = o;
  }
}

// ---------------- Kernel B: main fused attention ----------------
// 512 thr; thread t owns cols 4t..4t+3 for all QT=8 q-rows -> z state = 8 x f4
// = 32 VGPRs (no 64-reg blob, no spill). wg = b + 8*qtile (XCD-friendly).
__global__ __launch_bounds__(TPB) void bayes_main_kernel(
    const float* __restrict__ qg, const unsigned short* __restrict__ kTg,
    const unsigned short* __restrict__ vbg,
    const float* __restrict__ maskg, const float* __restrict__ epsg,
    float* __restrict__ outg, float* __restrict__ attng, float* __restrict__ klws){
  const int b  = blockIdx.x & 7;
  const int qt = blockIdx.x >> 3;
  const int q0 = qt * QT;
  const int t  = threadIdx.x;
  const int lane = t & 63, w = t >> 6;

  __shared__ f4 qlds[QT][16];                    // 2 KB
  __shared__ unsigned short albf[2048][8];       // 32 KB attn bf16 [col][row]
  __shared__ unsigned short vbf[256*72];         // 36 KB va tile bf16, stride 72
  __shared__ float wr6[8][QT][6];                // 1.5 KB
  __shared__ float rowc1[QT], rowS2[QT], rowinv[QT], klrow[QT];

  if (t < 128) ((f4*)qlds)[t] = ((const f4*)qg)[(size_t)(b*NQ + q0)*16 + t];
  __syncthreads();

  // ---- pass A: alpha = q.k + 1 via bf16 kT streams ----
  f4 z4[QT];
  #pragma unroll
  for (int r = 0; r < QT; ++r) z4[r] = 1.0f;

  const unsigned short* kTb = kTg + (size_t)b*DM*NK + 4*t;
  #pragma unroll 1
  for (int dblk = 0; dblk < 16; ++dblk){
    f4 qv[QT];
    #pragma unroll
    for (int r = 0; r < QT; ++r) qv[r] = qlds[r][dblk];
    const unsigned short* kp = kTb + (size_t)(dblk*4)*NK;
    u32x2 kw0 = *(const u32x2*)(kp);
    u32x2 kw1 = *(const u32x2*)(kp + NK);
    u32x2 kw2 = *(const u32x2*)(kp + 2*NK);
    u32x2 kw3 = *(const u32x2*)(kp + 3*NK);
    #define PASSA_D(KW, COMP) { \
      float c0 = bflo(KW[0]), c1 = bfhi(KW[0]), c2 = bflo(KW[1]), c3 = bfhi(KW[1]); \
      _Pragma("unroll") \
      for (int r = 0; r < QT; ++r){ \
        float qc = qv[r].COMP; \
        z4[r].x = fmaf(qc, c0, z4[r].x); \
        z4[r].y = fmaf(qc, c1, z4[r].y); \
        z4[r].z = fmaf(qc, c2, z4[r].z); \
        z4[r].w = fmaf(qc, c3, z4[r].w); \
      } }
    PASSA_D(kw0, x) PASSA_D(kw1, y) PASSA_D(kw2, z) PASSA_D(kw3, w)
    #undef PASSA_D
  }

  // ---- sweep 1: mask read (f4), dirichlet sums ----
  unsigned mbits = 0;
  #pragma unroll
  for (int r = 0; r < QT; ++r){
    f4 m4 = __builtin_nontemporal_load(
        (const f4*)(maskg + ((size_t)(b*NQ) + q0 + r)*NK + 4*t));
    f4 a4 = z4[r];
    float a0 = 0, Sg = 0, Sadg = 0, Sdg = 0, Sinv = 0, lat = 0;
    #define D1(AC, MC, BIT) { \
      float a = (AC), m = (MC); \
      float psi, lg; psi_lgam(a, psi, lg); \
      float inv = frcp(a); \
      if (m != 0.0f) mbits |= (1u << (BIT)); \
      a0   = fmaf(a,     m, a0); \
      Sg   = fmaf(lg,    m, Sg); \
      Sadg = fmaf(a*psi, m, Sadg); \
      Sdg  = fmaf(psi,   m, Sdg); \
      Sinv = fmaf(inv,   m, Sinv); \
      lat += m; }
    D1(a4.x, m4.x, r*4+0) D1(a4.y, m4.y, r*4+1)
    D1(a4.z, m4.z, r*4+2) D1(a4.w, m4.w, r*4+3)
    #undef D1
    a0 = wave_sum(a0); Sg = wave_sum(Sg); Sadg = wave_sum(Sadg);
    Sdg = wave_sum(Sdg); Sinv = wave_sum(Sinv); lat = wave_sum(lat);
    if (lane == 0){
      wr6[w][r][0] = a0;  wr6[w][r][1] = Sg;  wr6[w][r][2] = Sadg;
      wr6[w][r][3] = Sdg; wr6[w][r][4] = Sinv; wr6[w][r][5] = lat;
    }
  }
  __syncthreads();
  if (t < QT){
    const int r = t;
    float A0 = 0, SG = 0, SADG = 0, SDG = 0, SINV = 0, LT = 0;
    #pragma unroll
    for (int ww = 0; ww < 8; ++ww){
      A0 += wr6[ww][r][0]; SG += wr6[ww][r][1]; SADG += wr6[ww][r][2];
      SDG += wr6[ww][r][3]; SINV += wr6[ww][r][4]; LT += wr6[ww][r][5];
    }
    float invLT = frcp(LT);
    rowc1[r] = 1.0f - 2.0f*invLT;
    rowS2[r] = SINV*invLT*invLT;
    // KLD combine in fp64 (cancellation of ~4e5 terms down to ~1e3)
    double A0d = (double)A0, csum = 0.0, prod = 1.0;
    #pragma unroll
    for (int s = 0; s < 7; ++s){
      if (A0d < 8.0){ csum += 1.0/A0d; prod *= A0d; A0d += 1.0; }
    }
    double lx = log(A0d), r1 = 1.0/A0d, r2 = r1*r1;
    double psiA = lx - 0.5*r1
                - r2*((1.0/12.0) - r2*((1.0/120.0) - r2*(1.0/252.0))) - csum;
    double lgA  = (A0d - 0.5)*lx - A0d + 0.918938533204672741
                + r1*((1.0/12.0) - r2*((1.0/360.0) - r2*(1.0/1260.0))) - log(prod);
    double kl = lgA - (double)SG + (double)SADG - psiA*(double)A0
              - ((double)SDG - psiA*(double)LT)*(1.0/(double)NK);
    klrow[r] = (float)fabs(kl);
  }
  __syncthreads();
  if (t == 0){
    float s = 0;
    #pragma unroll
    for (int r = 0; r < QT; ++r) s += klrow[r];
    klws[b*(NQ/QT) + qt] = s;
  }

  // ---- sweep 2: e2 = exp(log a + sigma*eps) (shift-invariant, no max-sub), row sums ----
  #pragma unroll
  for (int r = 0; r < QT; ++r){
    const float c1v = rowc1[r], S2v = rowS2[r];
    f4 e4 = __builtin_nontemporal_load(
        (const f4*)(epsg + ((size_t)(b*NQ) + q0 + r)*NK + 4*t));
    f4 a4 = z4[r], o;
    #define S2C(AC, EC, OC, BIT) { \
      if ((mbits >> (BIT)) & 1u){ \
        float la = __logf(AC); \
        float zz = fmaf(fmaf(c1v, frcp(AC), S2v), EC, la); \
        OC = __expf(zz); \
      } else OC = 0.0f; }
    S2C(a4.x, e4.x, o.x, r*4+0) S2C(a4.y, e4.y, o.y, r*4+1)
    S2C(a4.z, e4.z, o.z, r*4+2) S2C(a4.w, e4.w, o.w, r*4+3)
    #undef S2C
    z4[r] = o;
    float s = wave_sum(o.x + o.y + o.z + o.w);
    if (lane == 0) wr6[w][r][0] = s;
  }
  __syncthreads();
  if (t < QT){
    float s = 0;
    #pragma unroll
    for (int ww = 0; ww < 8; ++ww) s += wr6[ww][t][0];
    rowinv[t] = frcp(s);
  }
  __syncthreads();

  // ---- sweep 3: normalize, write attn (f4 nontemporal), stage bf16 [col][row] ----
  #pragma unroll
  for (int r = 0; r < QT; ++r){
    f4 av = z4[r] * rowinv[r];
    z4[r] = av;
    __builtin_nontemporal_store(av,
        (f4*)(attng + ((size_t)(b*NQ) + q0 + r)*NK + 4*t));
  }
  #pragma unroll
  for (int c = 0; c < 4; ++c){
    u32x4 pk = { packtr(z4[0][c], z4[1][c]), packtr(z4[2][c], z4[3][c]),
                 packtr(z4[4][c], z4[5][c]), packtr(z4[6][c], z4[7][c]) };
    *(u32x4*)&albf[4*t + c][0] = pk;
  }

  // ---- PV: out = attn @ va, bf16 LDS tiles ----
  const int d4 = t & 15, js = t >> 4;
  f4 acc[QT];
  #pragma unroll
  for (int r = 0; r < QT; ++r) acc[r] = 0.0f;
  const unsigned short* vbb = vbg + (size_t)b*NK*DM;
  #pragma unroll 1
  for (int tile = 0; tile < 8; ++tile){
    __syncthreads();                            // prev tile reads done (and albf writes, tile 0)
    #pragma unroll
    for (int s = 0; s < 8; ++s){
      int jl = js + 32*s;
      u32x2 vv = *(const u32x2*)(vbb + (size_t)(tile*256 + jl)*DM + 4*d4);
      *(u32x2*)&vbf[jl*72 + 4*d4] = vv;
    }
    __syncthreads();
    #pragma unroll
    for (int jj = 0; jj < 8; ++jj){
      int jl = js + 32*jj;
      u32x4 au = *(const u32x4*)&albf[tile*256 + jl][0];
      u32x2 vu = *(const u32x2*)&vbf[jl*72 + 4*d4];
      float v0 = bflo(vu[0]), v1 = bfhi(vu[0]), v2 = bflo(vu[1]), v3 = bfhi(vu[1]);
      float ar[QT] = { bflo(au[0]), bfhi(au[0]), bflo(au[1]), bfhi(au[1]),
                       bflo(au[2]), bfhi(au[2]), bflo(au[3]), bfhi(au[3]) };
      #pragma unroll
      for (int r = 0; r < QT; ++r){
        acc[r].x = fmaf(ar[r], v0, acc[r].x);
        acc[r].y = fmaf(ar[r], v1, acc[r].y);
        acc[r].z = fmaf(ar[r], v2, acc[r].z);
        acc[r].w = fmaf(ar[r], v3, acc[r].w);
      }
    }
  }
  // reduce the 4 js-subgroups within each wave (lanes l, l^16, l^32, l^48)
  #pragma unroll
  for (int r = 0; r < QT; ++r){
    #pragma unroll
    for (int c = 0; c < 4; ++c){
      float v = acc[r][c];
      v += __shfl_xor(v, 16);
      v += __shfl_xor(v, 32);
      acc[r][c] = v;
    }
  }
  __syncthreads();                               // vbf reads done; alias as pvred
  float* pvred = (float*)vbf;                    // [8 waves][16 d4][8 r] f4 = 16 KB
  if (lane < 16){
    #pragma unroll
    for (int r = 0; r < QT; ++r)
      *(f4*)&pvred[(((w*16) + lane)*8 + r)*4] = acc[r];
  }
  __syncthreads();
  {
    const int rr = t >> 6, dd = t & 63;
    float s = 0;
    #pragma unroll
    for (int ww = 0; ww < 8; ++ww)
      s += pvred[(((ww*16) + (dd >> 2))*8 + rr)*4 + (dd & 3)];
    outg[((size_t)(b*NQ) + q0 + rr)*DM + dd] = s;
  }
}

// ---------------- Kernel C: deterministic KLD reduce ----------------
__global__ __launch_bounds__(256) void kld_reduce_kernel(
    const float* __restrict__ klws, float* __restrict__ dst){
  float s = 0.0f;
  for (int i = threadIdx.x; i < BB*(NQ/QT); i += 256) s += klws[i];
  s = wave_sum(s);
  __shared__ float w4[4];
  if ((threadIdx.x & 63) == 0) w4[threadIdx.x >> 6] = s;
  __syncthreads();
  if (threadIdx.x == 0)
    dst[0] = (w4[0] + w4[1] + w4[2] + w4[3]) * (1.0f/((float)BB*(float)NQ));
}

extern "C" void kernel_launch(void* const* d_in, const int* in_sizes, int n_in,
                              void* d_out, int out_size, void* d_ws, size_t ws_size,
                              hipStream_t stream){
  const float* y    = (const float*)d_in[0];
  const float* x    = (const float*)d_in[1];
  const float* mask = (const float*)d_in[2];
  const float* eps  = (const float*)d_in[3];
  const float* Wq   = (const float*)d_in[4];
  const float* bq   = (const float*)d_in[5];
  const float* Wk   = (const float*)d_in[6];
  const float* bk   = (const float*)d_in[7];
  const float* Wv   = (const float*)d_in[8];
  const float* bv   = (const float*)d_in[9];

  float* out  = (float*)d_out;                       // [B,NQ,DM]
  float* attn = out  + (size_t)BB*NQ*DM;             // [B,NQ,NK]
  float* va   = attn + (size_t)BB*NQ*NK;             // [B,NK,DM]
  float* kld  = va   + (size_t)BB*NK*DM;             // [1]

  char* wsb = (char*)d_ws;
  float*          qws  = (float*)wsb;                                  // 4 MB
  float*          kws  = (float*)(wsb + (size_t)BB*NQ*DM*4);           // 4 MB
  unsigned short* kT   = (unsigned short*)(wsb + (size_t)BB*NQ*DM*8);  // 2 MB
  unsigned short* vabf = (unsigned short*)(wsb + (size_t)BB*NQ*DM*10); // 2 MB
  float*          klws = (float*)(wsb + (size_t)BB*NQ*DM*12);          // 8 KB

  dim3 gA((BB*NQ)/4, 3);
  hipLaunchKernelGGL(mlp3_kernel, gA, dim3(256), 0, stream,
                     y, x, Wq, bq, Wk, bk, Wv, bv, qws, kws, va, vabf);
  hipLaunchKernelGGL(ktrans_kernel, dim3(NK/64, BB), dim3(256), 0, stream, kws, kT);
  hipLaunchKernelGGL(bayes_main_kernel, dim3(BB*(NQ/QT)), dim3(TPB), 0, stream,
                     qws, kT, vabf, mask, eps, out, attn, klws);
  hipLaunchKernelGGL(kld_reduce_kernel, dim3(1), dim3(256), 0, stream, klws, kld);
}

// Round 5
// 270.496 us; speedup vs baseline: 2.6505x; 1.6323x over previous
//
#include <hip/hip_runtime.h>
#include <cstdint>
#include <cstddef>

#define BB 8
#define NQ 2048
#define NK 2048
#define DM 64
#define QT 16          // q-rows per block (MFMA M)
#define TPB 512
#define PST 2056       // Plds row stride in shorts (pad 8)

typedef float    f4    __attribute__((ext_vector_type(4)));
typedef short    s16x8 __attribute__((ext_vector_type(8)));
typedef unsigned u32x2 __attribute__((ext_vector_type(2)));

__device__ __forceinline__ float frcp(float x){
  float r = __builtin_amdgcn_rcpf(x);
  return r * (2.0f - x*r);
}
__device__ __forceinline__ float softplus(float v){
  return fmaxf(v, 0.0f) + log1pf(__expf(-fabsf(v)));
}
__device__ __forceinline__ float bflo(unsigned u){ return __uint_as_float(u << 16); }
__device__ __forceinline__ float bfhi(unsigned u){ return __uint_as_float(u & 0xffff0000u); }
__device__ __forceinline__ unsigned short f2bf(float f){
  unsigned u = __float_as_uint(f);
  return (unsigned short)((u + 0x7fffu + ((u >> 16) & 1u)) >> 16);
}
__device__ __forceinline__ unsigned pack_rne(float lo, float hi){
  return (unsigned)f2bf(lo) | ((unsigned)f2bf(hi) << 16);
}
// sum-reduce over the 32-lane half-wave group
__device__ __forceinline__ float red32(float v){
  #pragma unroll
  for (int s = 1; s < 32; s <<= 1) v += __shfl_xor(v, s);
  return v;
}

// digamma + gammaln for x >= 1 (shift-to-8 + Stirling). abs err < 1e-6.
__device__ __forceinline__ void psi_lgam(float x, float& psi, float& lg){
  float xs = x, csum = 0.0f, prod = 1.0f;
  if (__any(xs < 8.0f)){
    #pragma unroll
    for (int s = 0; s < 7; ++s){
      if (xs < 8.0f){ csum += frcp(xs); prod *= xs; xs += 1.0f; }
    }
  }
  float rx  = frcp(xs);
  float lx  = __logf(xs);
  float rx2 = rx*rx;
  psi = lx - 0.5f*rx
      - rx2*(0.0833333333333f - rx2*(0.00833333333333f - rx2*0.00396825396825f))
      - csum;
  lg  = (xs - 0.5f)*lx - xs + 0.91893853320467274f
      + rx*(0.0833333333333f - rx2*(0.00277777777778f - rx2*0.000793650793651f));
  if (__any(prod != 1.0f)) lg -= __logf(prod);
}

// ---------------- Kernel A: fused 3-layer MLPs (q, k, va) ----------------
__global__ __launch_bounds__(256) void mlp3_kernel(
    const float* __restrict__ y, const float* __restrict__ x,
    const float* __restrict__ Wq, const float* __restrict__ bq,
    const float* __restrict__ Wk, const float* __restrict__ bk,
    const float* __restrict__ Wv, const float* __restrict__ bv,
    unsigned short* __restrict__ qo, unsigned short* __restrict__ ko,
    float* __restrict__ vo){
  const int which = blockIdx.y;                 // 0:q 1:k 2:va
  const float* src = (which == 0) ? y : x;
  const float* W   = (which == 0) ? Wq : (which == 1 ? Wk : Wv);
  const float* bb  = (which == 0) ? bq : (which == 1 ? bk : bv);
  const bool last_sp = (which != 2);
  const int row0 = blockIdx.x * 4;
  const int r = threadIdx.x >> 6, c = threadIdx.x & 63;

  __shared__ float h[2][4][DM];
  __shared__ float Wl[DM][DM];

  h[0][r][c] = src[(size_t)(row0 + r)*DM + c];
  float acc = 0.0f;
  for (int l = 0; l < 3; ++l){
    __syncthreads();
    #pragma unroll
    for (int i = 0; i < 16; ++i)
      ((float*)Wl)[i*256 + threadIdx.x] = W[l*DM*DM + i*256 + threadIdx.x];
    __syncthreads();
    float wcol[DM];
    #pragma unroll
    for (int d = 0; d < DM; ++d) wcol[d] = Wl[d][c];
    acc = bb[l*DM + c];
    const float* hr = h[l & 1][r];
    #pragma unroll
    for (int d = 0; d < DM; ++d) acc = fmaf(hr[d], wcol[d], acc);
    if (l < 2 || last_sp) acc = softplus(acc);
    __syncthreads();
    h[(l + 1) & 1][r][c] = acc;
  }
  const size_t idx = (size_t)(row0 + r)*DM + c;
  if (which == 0)      qo[idx] = f2bf(acc);
  else if (which == 1) ko[idx] = f2bf(acc);
  else                 vo[idx] = acc;
}

// ---------------- Kernel A2: transpose va -> vaT[B][DM][NK] (bf16) ----------------
__global__ __launch_bounds__(256) void vatrans_kernel(
    const float* __restrict__ va, unsigned short* __restrict__ vaT){
  const int b = blockIdx.y, tile = blockIdx.x;  // tile of 64 rows
  const int t = threadIdx.x;
  __shared__ float ld[64][65];
  const float* src = va + (size_t)b*NK*DM + (size_t)tile*64*DM;
  #pragma unroll
  for (int p = 0; p < 4; ++p){
    int idx = t + p*256;                 // float4 index 0..1023
    int row = idx >> 4, c4 = idx & 15;
    f4 v = ((const f4*)src)[idx];
    ld[row][c4*4+0] = v.x; ld[row][c4*4+1] = v.y;
    ld[row][c4*4+2] = v.z; ld[row][c4*4+3] = v.w;
  }
  __syncthreads();
  unsigned short* dst = vaT + (size_t)b*DM*NK + (size_t)tile*64;
  #pragma unroll
  for (int p = 0; p < 4; ++p){
    int idx = t + p*256;
    int d = idx >> 4, j4 = idx & 15;
    u32x2 o = { pack_rne(ld[j4*4+0][d], ld[j4*4+1][d]),
                pack_rne(ld[j4*4+2][d], ld[j4*4+3][d]) };
    *(u32x2*)(dst + (size_t)d*NK + j4*4) = o;
  }
}

// ---------------- Kernel B: main fused attention (MFMA) ----------------
// 512 thr = 8 waves. QT=16 q-rows. Phase 1: S = qk via MFMA -> Plds bf16.
// Phase 2: per 32-lane row-group sweeps (Dirichlet sums, exp, attn write).
// Phase 3: PV via MFMA with Plds as A-operand, vaT as B-operand.
__global__ __launch_bounds__(TPB) void bayes_main_kernel(
    const unsigned short* __restrict__ qbf, const unsigned short* __restrict__ kbf,
    const unsigned short* __restrict__ vaT,
    const float* __restrict__ maskg, const float* __restrict__ epsg,
    float* __restrict__ outg, float* __restrict__ attng, float* __restrict__ klws){
  const int b  = blockIdx.x & 7;
  const int qt = blockIdx.x >> 3;
  const int q0 = qt * QT;
  const int t  = threadIdx.x;
  const int l  = t & 63, w = t >> 6;
  const int lm = l & 15, lg = l >> 4;

  __shared__ unsigned short Plds[QT][PST];   // 65792 B
  __shared__ float pvred[4][QT][16];         // 4 KB
  __shared__ float rowinvL[QT], klrow[QT];

  // ---- phase 1: S tiles via MFMA; wave w owns j in [256w, 256w+256) ----
  {
    const unsigned short* qrow = qbf + ((size_t)(b*NQ + q0 + lm))*DM + lg*8;
    s16x8 qa0 = *(const s16x8*)qrow;
    s16x8 qa1 = *(const s16x8*)(qrow + 32);
    #pragma unroll 2
    for (int tt = 0; tt < 16; ++tt){
      const int jt = w*16 + tt;
      const unsigned short* krow = kbf + ((size_t)(b*NK + jt*16 + lm))*DM + lg*8;
      s16x8 kb0 = *(const s16x8*)krow;
      s16x8 kb1 = *(const s16x8*)(krow + 32);
      f4 acc = {0.f, 0.f, 0.f, 0.f};
      acc = __builtin_amdgcn_mfma_f32_16x16x32_bf16(qa0, kb0, acc, 0, 0, 0);
      acc = __builtin_amdgcn_mfma_f32_16x16x32_bf16(qa1, kb1, acc, 0, 0, 0);
      #pragma unroll
      for (int r = 0; r < 4; ++r)
        Plds[lg*4 + r][jt*16 + lm] = f2bf(acc[r]);
    }
  }
  __syncthreads();

  // ---- phase 2: sweeps. 32-lane group owns one row; thread owns cols 4c+128k ----
  const int row = t >> 5, c = t & 31;
  const size_t rowoff = ((size_t)(b*NQ) + q0 + row)*NK;

  float a0 = 0, Sg = 0, Sadg = 0, Sdg = 0, Sinv = 0, lat = 0;
  unsigned long long mbits = 0;
  #pragma unroll 4
  for (int k = 0; k < 16; ++k){
    u32x2 sw = *(const u32x2*)&Plds[row][k*128 + c*4];
    f4 m4 = __builtin_nontemporal_load((const f4*)(maskg + rowoff + k*128 + c*4));
    const float av[4] = { bflo(sw[0]) + 1.0f, bfhi(sw[0]) + 1.0f,
                          bflo(sw[1]) + 1.0f, bfhi(sw[1]) + 1.0f };
    #pragma unroll
    for (int c4 = 0; c4 < 4; ++c4){
      float a = av[c4], m = m4[c4];
      if (m != 0.0f) mbits |= 1ull << (k*4 + c4);
      float psi, lg2; psi_lgam(a, psi, lg2);
      float inv = frcp(a);
      a0   = fmaf(a,     m, a0);
      Sg   = fmaf(lg2,   m, Sg);
      Sadg = fmaf(a*psi, m, Sadg);
      Sdg  = fmaf(psi,   m, Sdg);
      Sinv = fmaf(inv,   m, Sinv);
      lat += m;
    }
  }
  a0 = red32(a0); Sg = red32(Sg); Sadg = red32(Sadg);
  Sdg = red32(Sdg); Sinv = red32(Sinv); lat = red32(lat);

  const float invLT = frcp(lat);
  const float c1 = 1.0f - 2.0f*invLT;
  const float S2 = Sinv*invLT*invLT;
  if (c == 0){
    // KLD combine in fp64 (cancellation of ~4e5-size terms down to ~1e3)
    double A0d = (double)a0, csum = 0.0, prod = 1.0;
    #pragma unroll
    for (int s = 0; s < 7; ++s){
      if (A0d < 8.0){ csum += 1.0/A0d; prod *= A0d; A0d += 1.0; }
    }
    double lx = log(A0d), r1 = 1.0/A0d, r2 = r1*r1;
    double psiA = lx - 0.5*r1
                - r2*((1.0/12.0) - r2*((1.0/120.0) - r2*(1.0/252.0))) - csum;
    double lgA  = (A0d - 0.5)*lx - A0d + 0.918938533204672741
                + r1*((1.0/12.0) - r2*((1.0/360.0) - r2*(1.0/1260.0))) - log(prod);
    double kl = lgA - (double)Sg + (double)Sadg - psiA*(double)a0
              - ((double)Sdg - psiA*(double)lat)*(1.0/(double)NK);
    klrow[row] = (float)fabs(kl);
  }

  // sweep 2: e2 = exp(log a + sigma*eps) (shift-invariant, no max-sub), row sum
  float esum = 0.0f;
  #pragma unroll 4
  for (int k = 0; k < 16; ++k){
    u32x2 sw = *(const u32x2*)&Plds[row][k*128 + c*4];
    f4 e4 = __builtin_nontemporal_load((const f4*)(epsg + rowoff + k*128 + c*4));
    const float av[4] = { bflo(sw[0]) + 1.0f, bfhi(sw[0]) + 1.0f,
                          bflo(sw[1]) + 1.0f, bfhi(sw[1]) + 1.0f };
    float e2v[4];
    #pragma unroll
    for (int c4 = 0; c4 < 4; ++c4){
      float e2;
      if ((mbits >> (k*4 + c4)) & 1ull){
        float a = av[c4];
        float la = __logf(a);
        float zz = fmaf(fmaf(c1, frcp(a), S2), e4[c4], la);
        e2 = __expf(zz);
      } else e2 = 0.0f;
      e2v[c4] = e2;
      esum += e2;
    }
    u32x2 ow = { pack_rne(e2v[0], e2v[1]), pack_rne(e2v[2], e2v[3]) };
    *(u32x2*)&Plds[row][k*128 + c*4] = ow;
  }
  esum = red32(esum);
  const float rinv = frcp(esum);
  if (c == 0) rowinvL[row] = rinv;

  // sweep 3: normalized attn write (coalesced f4, nontemporal)
  #pragma unroll 4
  for (int k = 0; k < 16; ++k){
    u32x2 ew = *(const u32x2*)&Plds[row][k*128 + c*4];
    f4 o = { bflo(ew[0])*rinv, bfhi(ew[0])*rinv, bflo(ew[1])*rinv, bfhi(ew[1])*rinv };
    __builtin_nontemporal_store(o, (f4*)(attng + rowoff + k*128 + c*4));
  }
  __syncthreads();

  if (t == 0){
    float s = 0;
    #pragma unroll
    for (int r = 0; r < QT; ++r) s += klrow[r];
    klws[b*(NQ/QT) + qt] = s;
  }

  // ---- phase 3: PV via MFMA. wave w: d-tile (w&3), j-half (w>>2) ----
  const int dt = w & 3, jh = w >> 2;
  f4 oacc = {0.f, 0.f, 0.f, 0.f};
  const unsigned short* vrow = vaT + ((size_t)(b*DM) + dt*16 + lm)*NK + jh*1024 + lg*8;
  const unsigned short* prow = &Plds[lm][jh*1024 + lg*8];
  #pragma unroll 4
  for (int ks = 0; ks < 32; ++ks){
    s16x8 pa = *(const s16x8*)(prow + ks*32);
    s16x8 vb = *(const s16x8*)(vrow + ks*32);
    oacc = __builtin_amdgcn_mfma_f32_16x16x32_bf16(pa, vb, oacc, 0, 0, 0);
  }
  if (w >= 4){
    #pragma unroll
    for (int r = 0; r < 4; ++r) pvred[dt][lg*4 + r][lm] = oacc[r];
  }
  __syncthreads();
  if (w < 4){
    #pragma unroll
    for (int r = 0; r < 4; ++r){
      const int q = lg*4 + r;
      float v = (oacc[r] + pvred[dt][q][lm]) * rowinvL[q];
      outg[((size_t)(b*NQ) + q0 + q)*DM + dt*16 + lm] = v;
    }
  }
}

// ---------------- Kernel C: deterministic KLD reduce ----------------
__global__ __launch_bounds__(256) void kld_reduce_kernel(
    const float* __restrict__ klws, float* __restrict__ dst){
  float s = 0.0f;
  for (int i = threadIdx.x; i < BB*(NQ/QT); i += 256) s += klws[i];
  #pragma unroll
  for (int o = 32; o; o >>= 1) s += __shfl_down(s, o);
  __shared__ float w4[4];
  if ((threadIdx.x & 63) == 0) w4[threadIdx.x >> 6] = s;
  __syncthreads();
  if (threadIdx.x == 0)
    dst[0] = (w4[0] + w4[1] + w4[2] + w4[3]) * (1.0f/((float)BB*(float)NQ));
}

extern "C" void kernel_launch(void* const* d_in, const int* in_sizes, int n_in,
                              void* d_out, int out_size, void* d_ws, size_t ws_size,
                              hipStream_t stream){
  const float* y    = (const float*)d_in[0];
  const float* x    = (const float*)d_in[1];
  const float* mask = (const float*)d_in[2];
  const float* eps  = (const float*)d_in[3];
  const float* Wq   = (const float*)d_in[4];
  const float* bq   = (const float*)d_in[5];
  const float* Wk   = (const float*)d_in[6];
  const float* bk   = (const float*)d_in[7];
  const float* Wv   = (const float*)d_in[8];
  const float* bv   = (const float*)d_in[9];

  float* out  = (float*)d_out;                       // [B,NQ,DM]
  float* attn = out  + (size_t)BB*NQ*DM;             // [B,NQ,NK]
  float* va   = attn + (size_t)BB*NQ*NK;             // [B,NK,DM]
  float* kld  = va   + (size_t)BB*NK*DM;             // [1]

  char* wsb = (char*)d_ws;
  unsigned short* qbf  = (unsigned short*)wsb;                          // 2 MB
  unsigned short* kbf  = (unsigned short*)(wsb + (size_t)BB*NQ*DM*2);   // 2 MB
  unsigned short* vaT  = (unsigned short*)(wsb + (size_t)BB*NQ*DM*4);   // 2 MB
  float*          klws = (float*)(wsb + (size_t)BB*NQ*DM*6);            // 4 KB

  dim3 gA((BB*NQ)/4, 3);
  hipLaunchKernelGGL(mlp3_kernel, gA, dim3(256), 0, stream,
                     y, x, Wq, bq, Wk, bk, Wv, bv, qbf, kbf, va);
  hipLaunchKernelGGL(vatrans_kernel, dim3(NK/64, BB), dim3(256), 0, stream, va, vaT);
  hipLaunchKernelGGL(bayes_main_kernel, dim3(BB*(NQ/QT)), dim3(TPB), 0, stream,
                     qbf, kbf, vaT, mask, eps, out, attn, klws);
  hipLaunchKernelGGL(kld_reduce_kernel, dim3(1), dim3(256), 0, stream, klws, kld);
}

// Round 6
// 216.587 us; speedup vs baseline: 3.3102x; 1.2489x over previous
//
#include <hip/hip_runtime.h>
#include <cstdint>
#include <cstddef>

#define BB 8
#define NQ 2048
#define NK 2048
#define DM 64
#define QT 16          // q-rows per block (MFMA M)
#define TPB 512
#define PST 2056       // Plds row stride in shorts (pad 8)

typedef float    f4    __attribute__((ext_vector_type(4)));
typedef short    s16x8 __attribute__((ext_vector_type(8)));
typedef unsigned u32x2 __attribute__((ext_vector_type(2)));

__device__ __forceinline__ float frcp(float x){            // Newton-refined (row-level use)
  float r = __builtin_amdgcn_rcpf(x);
  return r * (2.0f - x*r);
}
__device__ __forceinline__ float softplus(float v){
  return fmaxf(v, 0.0f) + log1pf(__expf(-fabsf(v)));
}
__device__ __forceinline__ float bflo(unsigned u){ return __uint_as_float(u << 16); }
__device__ __forceinline__ float bfhi(unsigned u){ return __uint_as_float(u & 0xffff0000u); }
__device__ __forceinline__ unsigned short f2bf(float f){
  unsigned u = __float_as_uint(f);
  return (unsigned short)((u + 0x7fffu + ((u >> 16) & 1u)) >> 16);
}
__device__ __forceinline__ unsigned pack_rne(float lo, float hi){
  return (unsigned)f2bf(lo) | ((unsigned)f2bf(hi) << 16);
}
// sum-reduce over the 32-lane half-wave group
__device__ __forceinline__ float red32(float v){
  #pragma unroll
  for (int s = 1; s < 32; s <<= 1) v += __shfl_xor(v, s);
  return v;
}

// ---------------- Kernel A: fused 3-layer MLPs (q, k, va), 16 rows/block ----------------
__global__ __launch_bounds__(256) void mlp3_kernel(
    const float* __restrict__ y, const float* __restrict__ x,
    const float* __restrict__ Wq, const float* __restrict__ bq,
    const float* __restrict__ Wk, const float* __restrict__ bk,
    const float* __restrict__ Wv, const float* __restrict__ bv,
    unsigned short* __restrict__ qo, unsigned short* __restrict__ ko,
    float* __restrict__ vo){
  const int which = blockIdx.y;                 // 0:q 1:k 2:va
  const float* src = (which == 0) ? y : x;
  const float* W   = (which == 0) ? Wq : (which == 1 ? Wk : Wv);
  const float* bb  = (which == 0) ? bq : (which == 1 ? bk : bv);
  const bool last_sp = (which != 2);
  const int row0 = blockIdx.x * 16;
  const int r = threadIdx.x >> 6, c = threadIdx.x & 63;   // r: 4-row group

  __shared__ float h[2][16][DM];
  __shared__ float Wl[DM][DM];

  #pragma unroll
  for (int i = 0; i < 4; ++i)
    h[0][r*4 + i][c] = src[(size_t)(row0 + r*4 + i)*DM + c];

  f4 acc = {0.f,0.f,0.f,0.f};
  for (int l = 0; l < 3; ++l){
    __syncthreads();
    #pragma unroll
    for (int i = 0; i < 16; ++i)
      ((float*)Wl)[i*256 + threadIdx.x] = W[l*DM*DM + i*256 + threadIdx.x];
    __syncthreads();
    float wcol[DM];
    #pragma unroll
    for (int d = 0; d < DM; ++d) wcol[d] = Wl[d][c];
    const float bc = bb[l*DM + c];
    acc = (f4){bc, bc, bc, bc};
    const float* h0 = h[l & 1][r*4 + 0];
    const float* h1 = h[l & 1][r*4 + 1];
    const float* h2 = h[l & 1][r*4 + 2];
    const float* h3 = h[l & 1][r*4 + 3];
    #pragma unroll
    for (int d = 0; d < DM; ++d){
      const float wv = wcol[d];
      acc.x = fmaf(h0[d], wv, acc.x);
      acc.y = fmaf(h1[d], wv, acc.y);
      acc.z = fmaf(h2[d], wv, acc.z);
      acc.w = fmaf(h3[d], wv, acc.w);
    }
    if (l < 2 || last_sp){
      acc.x = softplus(acc.x); acc.y = softplus(acc.y);
      acc.z = softplus(acc.z); acc.w = softplus(acc.w);
    }
    __syncthreads();
    #pragma unroll
    for (int i = 0; i < 4; ++i) h[(l + 1) & 1][r*4 + i][c] = acc[i];
  }
  #pragma unroll
  for (int i = 0; i < 4; ++i){
    const size_t idx = (size_t)(row0 + r*4 + i)*DM + c;
    if (which == 0)      qo[idx] = f2bf(acc[i]);
    else if (which == 1) ko[idx] = f2bf(acc[i]);
    else                 vo[idx] = acc[i];
  }
}

// ---------------- Kernel A2: transpose va -> vaT[B][DM][NK] (bf16) ----------------
__global__ __launch_bounds__(256) void vatrans_kernel(
    const float* __restrict__ va, unsigned short* __restrict__ vaT){
  const int b = blockIdx.y, tile = blockIdx.x;  // tile of 64 rows
  const int t = threadIdx.x;
  __shared__ float ld[64][65];
  const float* src = va + (size_t)b*NK*DM + (size_t)tile*64*DM;
  #pragma unroll
  for (int p = 0; p < 4; ++p){
    int idx = t + p*256;                 // float4 index 0..1023
    int row = idx >> 4, c4 = idx & 15;
    f4 v = ((const f4*)src)[idx];
    ld[row][c4*4+0] = v.x; ld[row][c4*4+1] = v.y;
    ld[row][c4*4+2] = v.z; ld[row][c4*4+3] = v.w;
  }
  __syncthreads();
  unsigned short* dst = vaT + (size_t)b*DM*NK + (size_t)tile*64;
  #pragma unroll
  for (int p = 0; p < 4; ++p){
    int idx = t + p*256;
    int d = idx >> 4, j4 = idx & 15;
    u32x2 o = { pack_rne(ld[j4*4+0][d], ld[j4*4+1][d]),
                pack_rne(ld[j4*4+2][d], ld[j4*4+3][d]) };
    *(u32x2*)(dst + (size_t)d*NK + j4*4) = o;
  }
}

// ---------------- Kernel B: main fused attention (MFMA) ----------------
// 512 thr = 8 waves. QT=16 q-rows. Phase 1: S = qk via MFMA -> Plds bf16.
// Phase 2: per 32-lane row-group sweeps (Dirichlet sums, exp, attn write).
// Phase 3: PV via MFMA with Plds as A-operand, vaT as B-operand.
__global__ __launch_bounds__(TPB) void bayes_main_kernel(
    const unsigned short* __restrict__ qbf, const unsigned short* __restrict__ kbf,
    const unsigned short* __restrict__ vaT,
    const float* __restrict__ maskg, const float* __restrict__ epsg,
    float* __restrict__ outg, float* __restrict__ attng, float* __restrict__ klws){
  const int b  = blockIdx.x & 7;
  const int qt = blockIdx.x >> 3;
  const int q0 = qt * QT;
  const int t  = threadIdx.x;
  const int l  = t & 63, w = t >> 6;
  const int lm = l & 15, lg = l >> 4;

  __shared__ unsigned short Plds[QT][PST];   // 65792 B
  __shared__ float pvred[4][QT][16];         // 4 KB
  __shared__ float rowinvL[QT], klrow[QT];

  // ---- phase 1: S tiles via MFMA; wave w owns j in [256w, 256w+256) ----
  {
    const unsigned short* qrow = qbf + ((size_t)(b*NQ + q0 + lm))*DM + lg*8;
    s16x8 qa0 = *(const s16x8*)qrow;
    s16x8 qa1 = *(const s16x8*)(qrow + 32);
    #pragma unroll 2
    for (int tt = 0; tt < 16; ++tt){
      const int jt = w*16 + tt;
      const unsigned short* krow = kbf + ((size_t)(b*NK + jt*16 + lm))*DM + lg*8;
      s16x8 kb0 = *(const s16x8*)krow;
      s16x8 kb1 = *(const s16x8*)(krow + 32);
      f4 acc = {0.f, 0.f, 0.f, 0.f};
      acc = __builtin_amdgcn_mfma_f32_16x16x32_bf16(qa0, kb0, acc, 0, 0, 0);
      acc = __builtin_amdgcn_mfma_f32_16x16x32_bf16(qa1, kb1, acc, 0, 0, 0);
      #pragma unroll
      for (int r = 0; r < 4; ++r)
        Plds[lg*4 + r][jt*16 + lm] = f2bf(acc[r]);
    }
  }
  __syncthreads();

  // ---- phase 2: sweeps. 32-lane group owns one row; thread owns cols 4c+128k ----
  const int row = t >> 5, c = t & 31;
  const size_t rowoff = ((size_t)(b*NQ) + q0 + row)*NK;

  // sweep 1: Dirichlet sums. Branchless shift-by-1 Stirling-at-2:
  //   psi(a) = log(a+1) - 1/(2(a+1)) - H2(1/(a+1)^2) - 1/a
  //   lgam(a) = (a+.5)log(a+1) - (a+1) + C + H2'(...)/(a+1) - log(a)
  // trunc err <= 1.6e-5 (a=1 worst case) vs per-element bias budget ~4e-3.
  float a0 = 0, Sg = 0, Sadg = 0, Sdg = 0, Sinv = 0, lat = 0;
  unsigned long long mbits = 0;
  #pragma unroll 4
  for (int k = 0; k < 16; ++k){
    u32x2 sw = *(const u32x2*)&Plds[row][k*128 + c*4];
    f4 m4 = __builtin_nontemporal_load((const f4*)(maskg + rowoff + k*128 + c*4));
    const float av[4] = { bflo(sw[0]) + 1.0f, bfhi(sw[0]) + 1.0f,
                          bflo(sw[1]) + 1.0f, bfhi(sw[1]) + 1.0f };
    #pragma unroll
    for (int c4 = 0; c4 < 4; ++c4){
      float a = av[c4], m = m4[c4];
      if (m != 0.0f) mbits |= 1ull << (k*4 + c4);
      float inv = __builtin_amdgcn_rcpf(a);
      float la  = __logf(a);
      float xs  = a + 1.0f;
      float lxs = __logf(xs);
      float rxs = __builtin_amdgcn_rcpf(xs);
      float rx2 = rxs*rxs;
      float t1  = fmaf(-rx2, 1.0f/252.0f, 1.0f/120.0f);
      float t2  = fmaf(-rx2, t1, 1.0f/12.0f);
      float psi = fmaf(-rx2, t2, fmaf(-0.5f, rxs, lxs)) - inv;
      float u1  = fmaf(-rx2, 1.0f/1260.0f, 1.0f/360.0f);
      float u2  = fmaf(-rx2, u1, 1.0f/12.0f);
      float lg2 = fmaf(xs - 0.5f, lxs, fmaf(rxs, u2, 0.91893853320467274f))
                - xs - la;
      a0   = fmaf(a,     m, a0);
      Sg   = fmaf(lg2,   m, Sg);
      Sadg = fmaf(a*psi, m, Sadg);
      Sdg  = fmaf(psi,   m, Sdg);
      Sinv = fmaf(inv,   m, Sinv);
      lat += m;
    }
  }
  a0 = red32(a0); Sg = red32(Sg); Sadg = red32(Sadg);
  Sdg = red32(Sdg); Sinv = red32(Sinv); lat = red32(lat);

  const float invLT = frcp(lat);
  const float c1 = 1.0f - 2.0f*invLT;
  const float S2 = Sinv*invLT*invLT;
  if (c == 0){
    // KLD combine in fp64 (cancellation of ~4e5-size terms down to ~1e3)
    double A0d = (double)a0, csum = 0.0, prod = 1.0;
    #pragma unroll
    for (int s = 0; s < 7; ++s){
      if (A0d < 8.0){ csum += 1.0/A0d; prod *= A0d; A0d += 1.0; }
    }
    double lx = log(A0d), r1 = 1.0/A0d, r2 = r1*r1;
    double psiA = lx - 0.5*r1
                - r2*((1.0/12.0) - r2*((1.0/120.0) - r2*(1.0/252.0))) - csum;
    double lgA  = (A0d - 0.5)*lx - A0d + 0.918938533204672741
                + r1*((1.0/12.0) - r2*((1.0/360.0) - r2*(1.0/1260.0))) - log(prod);
    double kl = lgA - (double)Sg + (double)Sadg - psiA*(double)a0
              - ((double)Sdg - psiA*(double)lat)*(1.0/(double)NK);
    klrow[row] = (float)fabs(kl);
  }

  // sweep 2: e2 = alpha * exp(sigma*eps)  (== exp(log a + sig e); no log, no max-sub)
  float esum = 0.0f;
  #pragma unroll 4
  for (int k = 0; k < 16; ++k){
    u32x2 sw = *(const u32x2*)&Plds[row][k*128 + c*4];
    f4 e4 = __builtin_nontemporal_load((const f4*)(epsg + rowoff + k*128 + c*4));
    const float av[4] = { bflo(sw[0]) + 1.0f, bfhi(sw[0]) + 1.0f,
                          bflo(sw[1]) + 1.0f, bfhi(sw[1]) + 1.0f };
    float e2v[4];
    #pragma unroll
    for (int c4 = 0; c4 < 4; ++c4){
      float e2 = 0.0f;
      if ((mbits >> (k*4 + c4)) & 1ull){
        float a = av[c4];
        float sig = fmaf(c1, __builtin_amdgcn_rcpf(a), S2);
        e2 = a * __expf(sig * e4[c4]);
      }
      e2v[c4] = e2;
      esum += e2;
    }
    u32x2 ow = { pack_rne(e2v[0], e2v[1]), pack_rne(e2v[2], e2v[3]) };
    *(u32x2*)&Plds[row][k*128 + c*4] = ow;
  }
  esum = red32(esum);
  const float rinv = frcp(esum);
  if (c == 0) rowinvL[row] = rinv;

  // sweep 3: normalized attn write (coalesced f4, nontemporal)
  #pragma unroll 4
  for (int k = 0; k < 16; ++k){
    u32x2 ew = *(const u32x2*)&Plds[row][k*128 + c*4];
    f4 o = { bflo(ew[0])*rinv, bfhi(ew[0])*rinv, bflo(ew[1])*rinv, bfhi(ew[1])*rinv };
    __builtin_nontemporal_store(o, (f4*)(attng + rowoff + k*128 + c*4));
  }
  __syncthreads();

  if (t == 0){
    float s = 0;
    #pragma unroll
    for (int r = 0; r < QT; ++r) s += klrow[r];
    klws[b*(NQ/QT) + qt] = s;
  }

  // ---- phase 3: PV via MFMA. wave w: d-tile (w&3), j-half (w>>2) ----
  const int dt = w & 3, jh = w >> 2;
  f4 oacc = {0.f, 0.f, 0.f, 0.f};
  const unsigned short* vrow = vaT + ((size_t)(b*DM) + dt*16 + lm)*NK + jh*1024 + lg*8;
  const unsigned short* prow = &Plds[lm][jh*1024 + lg*8];
  #pragma unroll 4
  for (int ks = 0; ks < 32; ++ks){
    s16x8 pa = *(const s16x8*)(prow + ks*32);
    s16x8 vb = *(const s16x8*)(vrow + ks*32);
    oacc = __builtin_amdgcn_mfma_f32_16x16x32_bf16(pa, vb, oacc, 0, 0, 0);
  }
  if (w >= 4){
    #pragma unroll
    for (int r = 0; r < 4; ++r) pvred[dt][lg*4 + r][lm] = oacc[r];
  }
  __syncthreads();
  if (w < 4){
    #pragma unroll
    for (int r = 0; r < 4; ++r){
      const int q = lg*4 + r;
      float v = (oacc[r] + pvred[dt][q][lm]) * rowinvL[q];
      outg[((size_t)(b*NQ) + q0 + q)*DM + dt*16 + lm] = v;
    }
  }
}

// ---------------- Kernel C: deterministic KLD reduce ----------------
__global__ __launch_bounds__(256) void kld_reduce_kernel(
    const float* __restrict__ klws, float* __restrict__ dst){
  float s = 0.0f;
  for (int i = threadIdx.x; i < BB*(NQ/QT); i += 256) s += klws[i];
  #pragma unroll
  for (int o = 32; o; o >>= 1) s += __shfl_down(s, o);
  __shared__ float w4[4];
  if ((threadIdx.x & 63) == 0) w4[threadIdx.x >> 6] = s;
  __syncthreads();
  if (threadIdx.x == 0)
    dst[0] = (w4[0] + w4[1] + w4[2] + w4[3]) * (1.0f/((float)BB*(float)NQ));
}

extern "C" void kernel_launch(void* const* d_in, const int* in_sizes, int n_in,
                              void* d_out, int out_size, void* d_ws, size_t ws_size,
                              hipStream_t stream){
  const float* y    = (const float*)d_in[0];
  const float* x    = (const float*)d_in[1];
  const float* mask = (const float*)d_in[2];
  const float* eps  = (const float*)d_in[3];
  const float* Wq   = (const float*)d_in[4];
  const float* bq   = (const float*)d_in[5];
  const float* Wk   = (const float*)d_in[6];
  const float* bk   = (const float*)d_in[7];
  const float* Wv   = (const float*)d_in[8];
  const float* bv   = (const float*)d_in[9];

  float* out  = (float*)d_out;                       // [B,NQ,DM]
  float* attn = out  + (size_t)BB*NQ*DM;             // [B,NQ,NK]
  float* va   = attn + (size_t)BB*NQ*NK;             // [B,NK,DM]
  float* kld  = va   + (size_t)BB*NK*DM;             // [1]

  char* wsb = (char*)d_ws;
  unsigned short* qbf  = (unsigned short*)wsb;                          // 2 MB
  unsigned short* kbf  = (unsigned short*)(wsb + (size_t)BB*NQ*DM*2);   // 2 MB
  unsigned short* vaT  = (unsigned short*)(wsb + (size_t)BB*NQ*DM*4);   // 2 MB
  float*          klws = (float*)(wsb + (size_t)BB*NQ*DM*6);            // 4 KB

  dim3 gA((BB*NQ)/16, 3);
  hipLaunchKernelGGL(mlp3_kernel, gA, dim3(256), 0, stream,
                     y, x, Wq, bq, Wk, bk, Wv, bv, qbf, kbf, va);
  hipLaunchKernelGGL(vatrans_kernel, dim3(NK/64, BB), dim3(256), 0, stream, va, vaT);
  hipLaunchKernelGGL(bayes_main_kernel, dim3(BB*(NQ/QT)), dim3(TPB), 0, stream,
                     qbf, kbf, vaT, mask, eps, out, attn, klws);
  hipLaunchKernelGGL(kld_reduce_kernel, dim3(1), dim3(256), 0, stream, klws, kld);
}

// Round 7
// 202.295 us; speedup vs baseline: 3.5441x; 1.0706x over previous
//
#include <hip/hip_runtime.h>
#include <cstdint>
#include <cstddef>

#define BB 8
#define NQ 2048
#define NK 2048
#define DM 64
#define QT 16          // q-rows per main block (MFMA M)
#define TPB 1024
#define PST 2056       // Plds row stride in shorts (pad 8)

typedef float    f4    __attribute__((ext_vector_type(4)));
typedef short    s16x8 __attribute__((ext_vector_type(8)));
typedef unsigned u32x2 __attribute__((ext_vector_type(2)));
typedef unsigned u32x4 __attribute__((ext_vector_type(4)));

__device__ __forceinline__ float frcp(float x){            // Newton-refined
  float r = __builtin_amdgcn_rcpf(x);
  return r * (2.0f - x*r);
}
__device__ __forceinline__ float softplus(float v){
  return fmaxf(v, 0.0f) + log1pf(__expf(-fabsf(v)));
}
__device__ __forceinline__ float bflo(unsigned u){ return __uint_as_float(u << 16); }
__device__ __forceinline__ float bfhi(unsigned u){ return __uint_as_float(u & 0xffff0000u); }
__device__ __forceinline__ unsigned short f2bf(float f){
  unsigned u = __float_as_uint(f);
  return (unsigned short)((u + 0x7fffu + ((u >> 16) & 1u)) >> 16);
}
__device__ __forceinline__ unsigned pack_rne(float lo, float hi){
  return (unsigned)f2bf(lo) | ((unsigned)f2bf(hi) << 16);
}
// full-wave (64-lane) butterfly sum; result in ALL lanes
__device__ __forceinline__ float red64(float v){
  #pragma unroll
  for (int s = 1; s < 64; s <<= 1) v += __shfl_xor(v, s);
  return v;
}

// ---------------- Kernel A: fused 3-layer MLPs via MFMA (q, k, va) --------
// 256 thr = 4 waves; block owns 64 rows. W (64x64) staged transposed in LDS
// bf16; activations live in LDS bf16 between layers. vaT transpose fused.
__global__ __launch_bounds__(256) void mlp3_kernel(
    const float* __restrict__ y, const float* __restrict__ x,
    const float* __restrict__ Wq, const float* __restrict__ bq,
    const float* __restrict__ Wk, const float* __restrict__ bk,
    const float* __restrict__ Wv, const float* __restrict__ bv,
    unsigned short* __restrict__ qo, unsigned short* __restrict__ ko,
    float* __restrict__ vo, unsigned short* __restrict__ vaT){
  const int which = blockIdx.y;                 // 0:q 1:k 2:va
  const float* src = (which == 0) ? y : x;
  const float* W   = (which == 0) ? Wq : (which == 1 ? Wk : Wv);
  const float* bb  = (which == 0) ? bq : (which == 1 ? bk : bv);
  const int row0 = blockIdx.x * 64;
  const int t = threadIdx.x;
  const int lane = t & 63, w = t >> 6, lm = lane & 15, lg = lane >> 4;

  __shared__ unsigned short Xl[64][72];   // activations bf16
  __shared__ unsigned short Wt[64][72];   // W^T bf16: Wt[n][k]
  __shared__ float bl[64];

  // stage X (64 rows x 64 f32 -> bf16)
  #pragma unroll
  for (int p = 0; p < 4; ++p){
    int idx = t + p*256;                  // f4 index
    int r = idx >> 4, c4 = idx & 15;
    f4 v = ((const f4*)(src + (size_t)row0*DM))[idx];
    u32x2 o = { pack_rne(v.x, v.y), pack_rne(v.z, v.w) };
    *(u32x2*)&Xl[r][c4*4] = o;
  }

  const int wr = w * 16;                  // this wave's 16 rows
  for (int l = 0; l < 3; ++l){
    __syncthreads();
    #pragma unroll
    for (int p = 0; p < 4; ++p){          // stage W^T for layer l
      int idx = t + p*256;
      int k = idx >> 4, c4 = idx & 15;
      f4 v = ((const f4*)(W + l*DM*DM))[idx];
      Wt[c4*4+0][k] = f2bf(v.x);
      Wt[c4*4+1][k] = f2bf(v.y);
      Wt[c4*4+2][k] = f2bf(v.z);
      Wt[c4*4+3][k] = f2bf(v.w);
    }
    if (t < 64) bl[t] = bb[l*DM + t];
    __syncthreads();
    const bool sp = (l < 2) || (which != 2);
    s16x8 a0 = *(const s16x8*)&Xl[wr + lm][lg*8];
    s16x8 a1 = *(const s16x8*)&Xl[wr + lm][32 + lg*8];
    f4 outv[4];
    #pragma unroll
    for (int nt = 0; nt < 4; ++nt){
      s16x8 b0 = *(const s16x8*)&Wt[nt*16 + lm][lg*8];
      s16x8 b1 = *(const s16x8*)&Wt[nt*16 + lm][32 + lg*8];
      f4 acc = {0.f, 0.f, 0.f, 0.f};
      acc = __builtin_amdgcn_mfma_f32_16x16x32_bf16(a0, b0, acc, 0, 0, 0);
      acc = __builtin_amdgcn_mfma_f32_16x16x32_bf16(a1, b1, acc, 0, 0, 0);
      const float bc = bl[nt*16 + lm];
      #pragma unroll
      for (int r = 0; r < 4; ++r){
        float vv = acc[r] + bc;
        if (sp) vv = softplus(vv);
        acc[r] = vv;
      }
      outv[nt] = acc;
    }
    // write back (true data-dep on a0/a1 orders vs own-row reads; rows disjoint per wave)
    #pragma unroll
    for (int nt = 0; nt < 4; ++nt)
      #pragma unroll
      for (int r = 0; r < 4; ++r)
        Xl[wr + lg*4 + r][nt*16 + lm] = f2bf(outv[nt][r]);
  }
  __syncthreads();

  if (which != 2){
    unsigned short* dst = ((which == 0) ? qo : ko) + (size_t)row0*DM;
    #pragma unroll
    for (int p = 0; p < 4; ++p){
      int idx = t + p*256;
      int r = idx >> 4, c4 = idx & 15;
      u32x2 u = *(const u32x2*)&Xl[r][c4*4];
      *(u32x2*)(dst + (size_t)idx*4) = u;
    }
  } else {
    // va f32 (widened bf16 — identical values to what PV consumes)
    #pragma unroll
    for (int p = 0; p < 4; ++p){
      int idx = t + p*256;
      int r = idx >> 4, c4 = idx & 15;
      u32x2 u = *(const u32x2*)&Xl[r][c4*4];
      f4 v = { bflo(u[0]), bfhi(u[0]), bflo(u[1]), bfhi(u[1]) };
      ((f4*)(vo + (size_t)row0*DM))[idx] = v;
    }
    // fused vaT transpose: vaT[b][d][j]
    const int bidx = row0 >> 11, jb = row0 & 2047;
    const int d = t >> 2, rs = t & 3;
    u32x4 o0, o1;
    #pragma unroll
    for (int i = 0; i < 4; ++i)
      o0[i] = (unsigned)Xl[rs*16 + 2*i][d] | ((unsigned)Xl[rs*16 + 2*i + 1][d] << 16);
    #pragma unroll
    for (int i = 0; i < 4; ++i)
      o1[i] = (unsigned)Xl[rs*16 + 8 + 2*i][d] | ((unsigned)Xl[rs*16 + 9 + 2*i][d] << 16);
    unsigned short* dst = vaT + ((size_t)bidx*DM + d)*NK + jb + rs*16;
    *(u32x4*)dst       = o0;
    *(u32x4*)(dst + 8) = o1;
  }
}

// ---------------- Kernel B: main fused attention (MFMA, 1024 thr) ----------
// 16 waves; wave w owns q-row w in the sweeps (64 lanes/row -> pure in-wave
// butterflies, rowinv stays in registers). 2 blocks/CU -> 32 waves/CU.
__global__ __launch_bounds__(TPB, 4) void bayes_main_kernel(
    const unsigned short* __restrict__ qbf, const unsigned short* __restrict__ kbf,
    const unsigned short* __restrict__ vaT,
    const float* __restrict__ maskg, const float* __restrict__ epsg,
    float* __restrict__ outg, float* __restrict__ attng, float* __restrict__ klws){
  const int b  = blockIdx.x & 7;
  const int qt = blockIdx.x >> 3;
  const int q0 = qt * QT;
  const int t  = threadIdx.x;
  const int lane = t & 63, w = t >> 6;
  const int lm = lane & 15, lg = lane >> 4;

  __shared__ unsigned short Plds[QT][PST];   // 65792 B; aliased as f32 for PV reduce
  __shared__ float klrow[QT];

  // ---- phase 1: S = qk via MFMA; wave w owns j-tiles [8w, 8w+8) ----
  {
    const unsigned short* qrow = qbf + ((size_t)(b*NQ + q0 + lm))*DM + lg*8;
    s16x8 qa0 = *(const s16x8*)qrow;
    s16x8 qa1 = *(const s16x8*)(qrow + 32);
    #pragma unroll 2
    for (int tt = 0; tt < 8; ++tt){
      const int jt = w*8 + tt;
      const unsigned short* krow = kbf + ((size_t)(b*NK + jt*16 + lm))*DM + lg*8;
      s16x8 kb0 = *(const s16x8*)krow;
      s16x8 kb1 = *(const s16x8*)(krow + 32);
      f4 acc = {0.f, 0.f, 0.f, 0.f};
      acc = __builtin_amdgcn_mfma_f32_16x16x32_bf16(qa0, kb0, acc, 0, 0, 0);
      acc = __builtin_amdgcn_mfma_f32_16x16x32_bf16(qa1, kb1, acc, 0, 0, 0);
      #pragma unroll
      for (int r = 0; r < 4; ++r)
        Plds[lg*4 + r][jt*16 + lm] = f2bf(acc[r]);
    }
  }
  __syncthreads();

  // ---- phase 2: wave w sweeps row w; thread owns cols 4c + 256k (k<8) ----
  const int row = w, c = lane;
  const size_t rowoff = ((size_t)(b*NQ) + q0 + row)*NK;

  // sweep 1: Dirichlet sums (branchless shift-by-1 Stirling-at-2, as round 6)
  float a0 = 0, Sg = 0, Sadg = 0, Sdg = 0, Sinv = 0, lat = 0;
  unsigned mbits = 0;
  #pragma unroll 2
  for (int k = 0; k < 8; ++k){
    u32x2 sw = *(const u32x2*)&Plds[row][k*256 + c*4];
    f4 m4 = __builtin_nontemporal_load((const f4*)(maskg + rowoff + k*256 + c*4));
    const float av[4] = { bflo(sw[0]) + 1.0f, bfhi(sw[0]) + 1.0f,
                          bflo(sw[1]) + 1.0f, bfhi(sw[1]) + 1.0f };
    #pragma unroll
    for (int c4 = 0; c4 < 4; ++c4){
      float a = av[c4], m = m4[c4];
      if (m != 0.0f) mbits |= 1u << (k*4 + c4);
      float inv = __builtin_amdgcn_rcpf(a);
      float la  = __logf(a);
      float xs  = a + 1.0f;
      float lxs = __logf(xs);
      float rxs = __builtin_amdgcn_rcpf(xs);
      float rx2 = rxs*rxs;
      float t1  = fmaf(-rx2, 1.0f/252.0f, 1.0f/120.0f);
      float t2  = fmaf(-rx2, t1, 1.0f/12.0f);
      float psi = fmaf(-rx2, t2, fmaf(-0.5f, rxs, lxs)) - inv;
      float u1  = fmaf(-rx2, 1.0f/1260.0f, 1.0f/360.0f);
      float u2  = fmaf(-rx2, u1, 1.0f/12.0f);
      float lg2 = fmaf(xs - 0.5f, lxs, fmaf(rxs, u2, 0.91893853320467274f))
                - xs - la;
      a0   = fmaf(a,     m, a0);
      Sg   = fmaf(lg2,   m, Sg);
      Sadg = fmaf(a*psi, m, Sadg);
      Sdg  = fmaf(psi,   m, Sdg);
      Sinv = fmaf(inv,   m, Sinv);
      lat += m;
    }
  }
  a0 = red64(a0); Sg = red64(Sg); Sadg = red64(Sadg);
  Sdg = red64(Sdg); Sinv = red64(Sinv); lat = red64(lat);

  const float invLT = frcp(lat);
  const float c1 = 1.0f - 2.0f*invLT;
  const float S2 = Sinv*invLT*invLT;
  if (lane == 0){
    // KLD combine in fp64 (cancellation of ~4e5-size terms down to ~1e3)
    double A0d = (double)a0, csum = 0.0, prod = 1.0;
    #pragma unroll
    for (int s = 0; s < 7; ++s){
      if (A0d < 8.0){ csum += 1.0/A0d; prod *= A0d; A0d += 1.0; }
    }
    double lx = log(A0d), r1 = 1.0/A0d, r2 = r1*r1;
    double psiA = lx - 0.5*r1
                - r2*((1.0/12.0) - r2*((1.0/120.0) - r2*(1.0/252.0))) - csum;
    double lgA  = (A0d - 0.5)*lx - A0d + 0.918938533204672741
                + r1*((1.0/12.0) - r2*((1.0/360.0) - r2*(1.0/1260.0))) - log(prod);
    double kl = lgA - (double)Sg + (double)Sadg - psiA*(double)a0
              - ((double)Sdg - psiA*(double)lat)*(1.0/(double)NK);
    klrow[row] = (float)fabs(kl);
  }

  // sweep 2: e2 = alpha * exp(sigma*eps), row sum
  float esum = 0.0f;
  #pragma unroll 2
  for (int k = 0; k < 8; ++k){
    u32x2 sw = *(const u32x2*)&Plds[row][k*256 + c*4];
    f4 e4 = __builtin_nontemporal_load((const f4*)(epsg + rowoff + k*256 + c*4));
    const float av[4] = { bflo(sw[0]) + 1.0f, bfhi(sw[0]) + 1.0f,
                          bflo(sw[1]) + 1.0f, bfhi(sw[1]) + 1.0f };
    float e2v[4];
    #pragma unroll
    for (int c4 = 0; c4 < 4; ++c4){
      float e2 = 0.0f;
      if ((mbits >> (k*4 + c4)) & 1u){
        float a = av[c4];
        float sig = fmaf(c1, __builtin_amdgcn_rcpf(a), S2);
        e2 = a * __expf(sig * e4[c4]);
      }
      e2v[c4] = e2;
      esum += e2;
    }
    u32x2 ow = { pack_rne(e2v[0], e2v[1]), pack_rne(e2v[2], e2v[3]) };
    *(u32x2*)&Plds[row][k*256 + c*4] = ow;
  }
  esum = red64(esum);
  const float rinv = frcp(esum);          // in ALL lanes of wave w

  // sweep 3: normalized attn write (coalesced f4, nontemporal)
  #pragma unroll 2
  for (int k = 0; k < 8; ++k){
    u32x2 ew = *(const u32x2*)&Plds[row][k*256 + c*4];
    f4 o = { bflo(ew[0])*rinv, bfhi(ew[0])*rinv, bflo(ew[1])*rinv, bfhi(ew[1])*rinv };
    __builtin_nontemporal_store(o, (f4*)(attng + rowoff + k*256 + c*4));
  }
  __syncthreads();

  if (t == 0){
    float s = 0;
    #pragma unroll
    for (int r = 0; r < QT; ++r) s += klrow[r];
    klws[b*(NQ/QT) + qt] = s;
  }

  // ---- phase 3: PV via MFMA. wave w: d-tile (w&3), j-quarter (w>>2) ----
  const int dt = w & 3, jq = w >> 2;
  f4 oacc = {0.f, 0.f, 0.f, 0.f};
  const unsigned short* vrow = vaT + ((size_t)(b*DM) + dt*16 + lm)*NK + jq*512 + lg*8;
  const unsigned short* prow = &Plds[lm][jq*512 + lg*8];
  #pragma unroll 4
  for (int ks = 0; ks < 16; ++ks){
    s16x8 pa = *(const s16x8*)(prow + ks*32);
    s16x8 vb = *(const s16x8*)(vrow + ks*32);
    oacc = __builtin_amdgcn_mfma_f32_16x16x32_bf16(pa, vb, oacc, 0, 0, 0);
  }
  __syncthreads();                         // all Plds reads done -> alias as f32
  float* pvredF = (float*)&Plds[0][0];     // [jq][dt][16 q][16 d] = 16 KB
  #pragma unroll
  for (int r = 0; r < 4; ++r)
    pvredF[(((jq*4 + dt)*16) + lg*4 + r)*16 + lm] = oacc[r];
  __syncthreads();
  {
    const int d = lane;                    // q-row = w; d = 0..63
    float s = 0;
    #pragma unroll
    for (int j2 = 0; j2 < 4; ++j2)
      s += pvredF[(((j2*4 + (d >> 4))*16) + w)*16 + (d & 15)];
    outg[((size_t)(b*NQ) + q0 + w)*DM + d] = s * rinv;
  }
}

// ---------------- Kernel C: deterministic KLD reduce ----------------
__global__ __launch_bounds__(256) void kld_reduce_kernel(
    const float* __restrict__ klws, float* __restrict__ dst){
  float s = 0.0f;
  for (int i = threadIdx.x; i < BB*(NQ/QT); i += 256) s += klws[i];
  #pragma unroll
  for (int o = 32; o; o >>= 1) s += __shfl_down(s, o);
  __shared__ float w4[4];
  if ((threadIdx.x & 63) == 0) w4[threadIdx.x >> 6] = s;
  __syncthreads();
  if (threadIdx.x == 0)
    dst[0] = (w4[0] + w4[1] + w4[2] + w4[3]) * (1.0f/((float)BB*(float)NQ));
}

extern "C" void kernel_launch(void* const* d_in, const int* in_sizes, int n_in,
                              void* d_out, int out_size, void* d_ws, size_t ws_size,
                              hipStream_t stream){
  const float* y    = (const float*)d_in[0];
  const float* x    = (const float*)d_in[1];
  const float* mask = (const float*)d_in[2];
  const float* eps  = (const float*)d_in[3];
  const float* Wq   = (const float*)d_in[4];
  const float* bq   = (const float*)d_in[5];
  const float* Wk   = (const float*)d_in[6];
  const float* bk   = (const float*)d_in[7];
  const float* Wv   = (const float*)d_in[8];
  const float* bv   = (const float*)d_in[9];

  float* out  = (float*)d_out;                       // [B,NQ,DM]
  float* attn = out  + (size_t)BB*NQ*DM;             // [B,NQ,NK]
  float* va   = attn + (size_t)BB*NQ*NK;             // [B,NK,DM]
  float* kld  = va   + (size_t)BB*NK*DM;             // [1]

  char* wsb = (char*)d_ws;
  unsigned short* qbf  = (unsigned short*)wsb;                          // 2 MB
  unsigned short* kbf  = (unsigned short*)(wsb + (size_t)BB*NQ*DM*2);   // 2 MB
  unsigned short* vaT  = (unsigned short*)(wsb + (size_t)BB*NQ*DM*4);   // 2 MB
  float*          klws = (float*)(wsb + (size_t)BB*NQ*DM*6);            // 4 KB

  dim3 gA((BB*NQ)/64, 3);
  hipLaunchKernelGGL(mlp3_kernel, gA, dim3(256), 0, stream,
                     y, x, Wq, bq, Wk, bk, Wv, bv, qbf, kbf, va, vaT);
  hipLaunchKernelGGL(bayes_main_kernel, dim3(BB*(NQ/QT)), dim3(TPB), 0, stream,
                     qbf, kbf, vaT, mask, eps, out, attn, klws);
  hipLaunchKernelGGL(kld_reduce_kernel, dim3(1), dim3(256), 0, stream, klws, kld);
}

// Round 8
// 156.734 us; speedup vs baseline: 4.5743x; 1.2907x over previous
//
#include <hip/hip_runtime.h>
#include <cstdint>
#include <cstddef>

#define BB 8
#define NQ 2048
#define NK 2048
#define DM 64
#define QT 16          // q-rows per main block (MFMA M)
#define TPB 512
#define PST 2056       // Plds row stride in shorts (pad 8)

typedef float    f4    __attribute__((ext_vector_type(4)));
typedef short    s16x8 __attribute__((ext_vector_type(8)));
typedef unsigned u32x2 __attribute__((ext_vector_type(2)));
typedef unsigned u32x4 __attribute__((ext_vector_type(4)));

__device__ __forceinline__ float frcp(float x){            // Newton-refined
  float r = __builtin_amdgcn_rcpf(x);
  return r * (2.0f - x*r);
}
__device__ __forceinline__ float softplus(float v){
  return fmaxf(v, 0.0f) + log1pf(__expf(-fabsf(v)));
}
__device__ __forceinline__ float bflo(unsigned u){ return __uint_as_float(u << 16); }
__device__ __forceinline__ float bfhi(unsigned u){ return __uint_as_float(u & 0xffff0000u); }
__device__ __forceinline__ unsigned short f2bf(float f){
  unsigned u = __float_as_uint(f);
  return (unsigned short)((u + 0x7fffu + ((u >> 16) & 1u)) >> 16);
}
__device__ __forceinline__ unsigned pack_rne(float lo, float hi){
  return (unsigned)f2bf(lo) | ((unsigned)f2bf(hi) << 16);
}
// sum-reduce over the 32-lane half-wave group (all lanes get result)
__device__ __forceinline__ float red32(float v){
  #pragma unroll
  for (int s = 1; s < 32; s <<= 1) v += __shfl_xor(v, s);
  return v;
}

// ---------------- Kernel A: fused 3-layer MLPs via MFMA (q, k, va) --------
// 256 thr = 4 waves; block owns 64 rows. W (64x64) staged transposed in LDS
// bf16; activations live in LDS bf16 between layers. vaT transpose fused.
__global__ __launch_bounds__(256) void mlp3_kernel(
    const float* __restrict__ y, const float* __restrict__ x,
    const float* __restrict__ Wq, const float* __restrict__ bq,
    const float* __restrict__ Wk, const float* __restrict__ bk,
    const float* __restrict__ Wv, const float* __restrict__ bv,
    unsigned short* __restrict__ qo, unsigned short* __restrict__ ko,
    float* __restrict__ vo, unsigned short* __restrict__ vaT){
  const int which = blockIdx.y;                 // 0:q 1:k 2:va
  const float* src = (which == 0) ? y : x;
  const float* W   = (which == 0) ? Wq : (which == 1 ? Wk : Wv);
  const float* bb  = (which == 0) ? bq : (which == 1 ? bk : bv);
  const int row0 = blockIdx.x * 64;
  const int t = threadIdx.x;
  const int lane = t & 63, w = t >> 6, lm = lane & 15, lg = lane >> 4;

  __shared__ unsigned short Xl[64][72];   // activations bf16
  __shared__ unsigned short Wt[64][72];   // W^T bf16: Wt[n][k]
  __shared__ float bl[64];

  // stage X (64 rows x 64 f32 -> bf16)
  #pragma unroll
  for (int p = 0; p < 4; ++p){
    int idx = t + p*256;                  // f4 index
    int r = idx >> 4, c4 = idx & 15;
    f4 v = ((const f4*)(src + (size_t)row0*DM))[idx];
    u32x2 o = { pack_rne(v.x, v.y), pack_rne(v.z, v.w) };
    *(u32x2*)&Xl[r][c4*4] = o;
  }

  const int wr = w * 16;                  // this wave's 16 rows
  for (int l = 0; l < 3; ++l){
    __syncthreads();
    #pragma unroll
    for (int p = 0; p < 4; ++p){          // stage W^T for layer l
      int idx = t + p*256;
      int k = idx >> 4, c4 = idx & 15;
      f4 v = ((const f4*)(W + l*DM*DM))[idx];
      Wt[c4*4+0][k] = f2bf(v.x);
      Wt[c4*4+1][k] = f2bf(v.y);
      Wt[c4*4+2][k] = f2bf(v.z);
      Wt[c4*4+3][k] = f2bf(v.w);
    }
    if (t < 64) bl[t] = bb[l*DM + t];
    __syncthreads();
    const bool sp = (l < 2) || (which != 2);
    s16x8 a0 = *(const s16x8*)&Xl[wr + lm][lg*8];
    s16x8 a1 = *(const s16x8*)&Xl[wr + lm][32 + lg*8];
    f4 outv[4];
    #pragma unroll
    for (int nt = 0; nt < 4; ++nt){
      s16x8 b0 = *(const s16x8*)&Wt[nt*16 + lm][lg*8];
      s16x8 b1 = *(const s16x8*)&Wt[nt*16 + lm][32 + lg*8];
      f4 acc = {0.f, 0.f, 0.f, 0.f};
      acc = __builtin_amdgcn_mfma_f32_16x16x32_bf16(a0, b0, acc, 0, 0, 0);
      acc = __builtin_amdgcn_mfma_f32_16x16x32_bf16(a1, b1, acc, 0, 0, 0);
      const float bc = bl[nt*16 + lm];
      #pragma unroll
      for (int r = 0; r < 4; ++r){
        float vv = acc[r] + bc;
        if (sp) vv = softplus(vv);
        acc[r] = vv;
      }
      outv[nt] = acc;
    }
    #pragma unroll
    for (int nt = 0; nt < 4; ++nt)
      #pragma unroll
      for (int r = 0; r < 4; ++r)
        Xl[wr + lg*4 + r][nt*16 + lm] = f2bf(outv[nt][r]);
  }
  __syncthreads();

  if (which != 2){
    unsigned short* dst = ((which == 0) ? qo : ko) + (size_t)row0*DM;
    #pragma unroll
    for (int p = 0; p < 4; ++p){
      int idx = t + p*256;
      int r = idx >> 4, c4 = idx & 15;
      u32x2 u = *(const u32x2*)&Xl[r][c4*4];
      *(u32x2*)(dst + (size_t)idx*4) = u;
    }
  } else {
    // va f32 (widened bf16 — identical values to what PV consumes)
    #pragma unroll
    for (int p = 0; p < 4; ++p){
      int idx = t + p*256;
      int r = idx >> 4, c4 = idx & 15;
      u32x2 u = *(const u32x2*)&Xl[r][c4*4];
      f4 v = { bflo(u[0]), bfhi(u[0]), bflo(u[1]), bfhi(u[1]) };
      ((f4*)(vo + (size_t)row0*DM))[idx] = v;
    }
    // fused vaT transpose: vaT[b][d][j]
    const int bidx = row0 >> 11, jb = row0 & 2047;
    const int d = t >> 2, rs = t & 3;
    u32x4 o0, o1;
    #pragma unroll
    for (int i = 0; i < 4; ++i)
      o0[i] = (unsigned)Xl[rs*16 + 2*i][d] | ((unsigned)Xl[rs*16 + 2*i + 1][d] << 16);
    #pragma unroll
    for (int i = 0; i < 4; ++i)
      o1[i] = (unsigned)Xl[rs*16 + 8 + 2*i][d] | ((unsigned)Xl[rs*16 + 9 + 2*i][d] << 16);
    unsigned short* dst = vaT + ((size_t)bidx*DM + d)*NK + jb + rs*16;
    *(u32x4*)dst       = o0;
    *(u32x4*)(dst + 8) = o1;
  }
}

// ---------------- Kernel B: main fused attention (MFMA, 512 thr) ----------
// 8 waves. Phase 1: S = qk via MFMA -> Plds bf16. Phase 2: 32-lane row-group
// sweeps with 8-deep f4 prefetch (mask/eps). Phase 3: PV via MFMA.
__global__ __launch_bounds__(TPB, 4) void bayes_main_kernel(
    const unsigned short* __restrict__ qbf, const unsigned short* __restrict__ kbf,
    const unsigned short* __restrict__ vaT,
    const float* __restrict__ maskg, const float* __restrict__ epsg,
    float* __restrict__ outg, float* __restrict__ attng, float* __restrict__ klws){
  const int b  = blockIdx.x & 7;
  const int qt = blockIdx.x >> 3;
  const int q0 = qt * QT;
  const int t  = threadIdx.x;
  const int lane = t & 63, w = t >> 6;
  const int lm = lane & 15, lg = lane >> 4;

  __shared__ unsigned short Plds[QT][PST];   // 65792 B
  __shared__ float pvred[4][QT][16];         // 4 KB
  __shared__ float rowinvL[QT], klrow[QT];

  // ---- phase 1: S tiles via MFMA; wave w owns j-tiles [16w, 16w+16) ----
  {
    const unsigned short* qrow = qbf + ((size_t)(b*NQ + q0 + lm))*DM + lg*8;
    s16x8 qa0 = *(const s16x8*)qrow;
    s16x8 qa1 = *(const s16x8*)(qrow + 32);
    #pragma unroll 2
    for (int tt = 0; tt < 16; ++tt){
      const int jt = w*16 + tt;
      const unsigned short* krow = kbf + ((size_t)(b*NK + jt*16 + lm))*DM + lg*8;
      s16x8 kb0 = *(const s16x8*)krow;
      s16x8 kb1 = *(const s16x8*)(krow + 32);
      f4 acc = {0.f, 0.f, 0.f, 0.f};
      acc = __builtin_amdgcn_mfma_f32_16x16x32_bf16(qa0, kb0, acc, 0, 0, 0);
      acc = __builtin_amdgcn_mfma_f32_16x16x32_bf16(qa1, kb1, acc, 0, 0, 0);
      #pragma unroll
      for (int r = 0; r < 4; ++r)
        Plds[lg*4 + r][jt*16 + lm] = f2bf(acc[r]);
    }
  }
  __syncthreads();

  // ---- phase 2: sweeps. 32-lane group owns one row; thread owns cols 4c+128k ----
  const int row = t >> 5, c = t & 31;
  const size_t rowoff = ((size_t)(b*NQ) + q0 + row)*NK;

  // sweep 1: Dirichlet sums (branchless shift-by-1 Stirling-at-2), 8-deep prefetch.
  float a0 = 0, Sg = 0, Sadg = 0, Sdg = 0, Sinv = 0, lat = 0;
  unsigned long long mbits = 0;
  #pragma unroll
  for (int h = 0; h < 2; ++h){
    f4 pm[8];
    #pragma unroll
    for (int k = 0; k < 8; ++k)    // plain loads: mask is reused across replays -> L3
      pm[k] = *(const f4*)(maskg + rowoff + (h*8 + k)*128 + c*4);
    #pragma unroll
    for (int k = 0; k < 8; ++k){
      const int kk = h*8 + k;
      u32x2 sw = *(const u32x2*)&Plds[row][kk*128 + c*4];
      const float av[4] = { bflo(sw[0]) + 1.0f, bfhi(sw[0]) + 1.0f,
                            bflo(sw[1]) + 1.0f, bfhi(sw[1]) + 1.0f };
      #pragma unroll
      for (int c4 = 0; c4 < 4; ++c4){
        float a = av[c4], m = pm[k][c4];
        if (m != 0.0f) mbits |= 1ull << (kk*4 + c4);
        float inv = __builtin_amdgcn_rcpf(a);
        float la  = __logf(a);
        float xs  = a + 1.0f;
        float lxs = __logf(xs);
        float rxs = __builtin_amdgcn_rcpf(xs);
        float rx2 = rxs*rxs;
        float t1  = fmaf(-rx2, 1.0f/252.0f, 1.0f/120.0f);
        float t2  = fmaf(-rx2, t1, 1.0f/12.0f);
        float psi = fmaf(-rx2, t2, fmaf(-0.5f, rxs, lxs)) - inv;
        float u1  = fmaf(-rx2, 1.0f/1260.0f, 1.0f/360.0f);
        float u2  = fmaf(-rx2, u1, 1.0f/12.0f);
        float lg2 = fmaf(xs - 0.5f, lxs, fmaf(rxs, u2, 0.91893853320467274f))
                  - xs - la;
        a0   = fmaf(a,     m, a0);
        Sg   = fmaf(lg2,   m, Sg);
        Sadg = fmaf(a*psi, m, Sadg);
        Sdg  = fmaf(psi,   m, Sdg);
        Sinv = fmaf(inv,   m, Sinv);
        lat += m;
      }
    }
  }
  a0 = red32(a0); Sg = red32(Sg); Sadg = red32(Sadg);
  Sdg = red32(Sdg); Sinv = red32(Sinv); lat = red32(lat);

  const float invLT = frcp(lat);
  const float c1 = 1.0f - 2.0f*invLT;
  const float S2 = Sinv*invLT*invLT;
  if (c == 0){
    // KLD combine in fp64 (cancellation of ~4e5-size terms down to ~1e3)
    double A0d = (double)a0, csum = 0.0, prod = 1.0;
    #pragma unroll
    for (int s = 0; s < 7; ++s){
      if (A0d < 8.0){ csum += 1.0/A0d; prod *= A0d; A0d += 1.0; }
    }
    double lx = log(A0d), r1 = 1.0/A0d, r2 = r1*r1;
    double psiA = lx - 0.5*r1
                - r2*((1.0/12.0) - r2*((1.0/120.0) - r2*(1.0/252.0))) - csum;
    double lgA  = (A0d - 0.5)*lx - A0d + 0.918938533204672741
                + r1*((1.0/12.0) - r2*((1.0/360.0) - r2*(1.0/1260.0))) - log(prod);
    double kl = lgA - (double)Sg + (double)Sadg - psiA*(double)a0
              - ((double)Sdg - psiA*(double)lat)*(1.0/(double)NK);
    klrow[row] = (float)fabs(kl);
  }

  // sweep 2: e2 = alpha * exp(sigma*eps), row sum; 8-deep prefetch on eps.
  float esum = 0.0f;
  #pragma unroll
  for (int h = 0; h < 2; ++h){
    f4 pe[8];
    #pragma unroll
    for (int k = 0; k < 8; ++k)
      pe[k] = __builtin_nontemporal_load(
          (const f4*)(epsg + rowoff + (h*8 + k)*128 + c*4));
    #pragma unroll
    for (int k = 0; k < 8; ++k){
      const int kk = h*8 + k;
      u32x2 sw = *(const u32x2*)&Plds[row][kk*128 + c*4];
      const float av[4] = { bflo(sw[0]) + 1.0f, bfhi(sw[0]) + 1.0f,
                            bflo(sw[1]) + 1.0f, bfhi(sw[1]) + 1.0f };
      float e2v[4];
      #pragma unroll
      for (int c4 = 0; c4 < 4; ++c4){
        float e2 = 0.0f;
        if ((mbits >> (kk*4 + c4)) & 1ull){
          float a = av[c4];
          float sig = fmaf(c1, __builtin_amdgcn_rcpf(a), S2);
          e2 = a * __expf(sig * pe[k][c4]);
        }
        e2v[c4] = e2;
        esum += e2;
      }
      u32x2 ow = { pack_rne(e2v[0], e2v[1]), pack_rne(e2v[2], e2v[3]) };
      *(u32x2*)&Plds[row][kk*128 + c*4] = ow;
    }
  }
  esum = red32(esum);
  const float rinv = frcp(esum);
  if (c == 0) rowinvL[row] = rinv;

  // sweep 3: normalized attn write (coalesced f4, nontemporal)
  #pragma unroll 4
  for (int k = 0; k < 16; ++k){
    u32x2 ew = *(const u32x2*)&Plds[row][k*128 + c*4];
    f4 o = { bflo(ew[0])*rinv, bfhi(ew[0])*rinv, bflo(ew[1])*rinv, bfhi(ew[1])*rinv };
    __builtin_nontemporal_store(o, (f4*)(attng + rowoff + k*128 + c*4));
  }
  __syncthreads();

  if (t == 0){
    float s = 0;
    #pragma unroll
    for (int r = 0; r < QT; ++r) s += klrow[r];
    klws[b*(NQ/QT) + qt] = s;
  }

  // ---- phase 3: PV via MFMA. wave w: d-tile (w&3), j-half (w>>2) ----
  const int dt = w & 3, jh = w >> 2;
  f4 oacc = {0.f, 0.f, 0.f, 0.f};
  const unsigned short* vrow = vaT + ((size_t)(b*DM) + dt*16 + lm)*NK + jh*1024 + lg*8;
  const unsigned short* prow = &Plds[lm][jh*1024 + lg*8];
  #pragma unroll 4
  for (int ks = 0; ks < 32; ++ks){
    s16x8 pa = *(const s16x8*)(prow + ks*32);
    s16x8 vb = *(const s16x8*)(vrow + ks*32);
    oacc = __builtin_amdgcn_mfma_f32_16x16x32_bf16(pa, vb, oacc, 0, 0, 0);
  }
  if (w >= 4){
    #pragma unroll
    for (int r = 0; r < 4; ++r) pvred[dt][lg*4 + r][lm] = oacc[r];
  }
  __syncthreads();
  if (w < 4){
    #pragma unroll
    for (int r = 0; r < 4; ++r){
      const int q = lg*4 + r;
      float v = (oacc[r] + pvred[dt][q][lm]) * rowinvL[q];
      outg[((size_t)(b*NQ) + q0 + q)*DM + dt*16 + lm] = v;
    }
  }
}

// ---------------- Kernel C: deterministic KLD reduce ----------------
__global__ __launch_bounds__(256) void kld_reduce_kernel(
    const float* __restrict__ klws, float* __restrict__ dst){
  float s = 0.0f;
  for (int i = threadIdx.x; i < BB*(NQ/QT); i += 256) s += klws[i];
  #pragma unroll
  for (int o = 32; o; o >>= 1) s += __shfl_down(s, o);
  __shared__ float w4[4];
  if ((threadIdx.x & 63) == 0) w4[threadIdx.x >> 6] = s;
  __syncthreads();
  if (threadIdx.x == 0)
    dst[0] = (w4[0] + w4[1] + w4[2] + w4[3]) * (1.0f/((float)BB*(float)NQ));
}

extern "C" void kernel_launch(void* const* d_in, const int* in_sizes, int n_in,
                              void* d_out, int out_size, void* d_ws, size_t ws_size,
                              hipStream_t stream){
  const float* y    = (const float*)d_in[0];
  const float* x    = (const float*)d_in[1];
  const float* mask = (const float*)d_in[2];
  const float* eps  = (const float*)d_in[3];
  const float* Wq   = (const float*)d_in[4];
  const float* bq   = (const float*)d_in[5];
  const float* Wk   = (const float*)d_in[6];
  const float* bk   = (const float*)d_in[7];
  const float* Wv   = (const float*)d_in[8];
  const float* bv   = (const float*)d_in[9];

  float* out  = (float*)d_out;                       // [B,NQ,DM]
  float* attn = out  + (size_t)BB*NQ*DM;             // [B,NQ,NK]
  float* va   = attn + (size_t)BB*NQ*NK;             // [B,NK,DM]
  float* kld  = va   + (size_t)BB*NK*DM;             // [1]

  char* wsb = (char*)d_ws;
  unsigned short* qbf  = (unsigned short*)wsb;                          // 2 MB
  unsigned short* kbf  = (unsigned short*)(wsb + (size_t)BB*NQ*DM*2);   // 2 MB
  unsigned short* vaT  = (unsigned short*)(wsb + (size_t)BB*NQ*DM*4);   // 2 MB
  float*          klws = (float*)(wsb + (size_t)BB*NQ*DM*6);            // 4 KB

  dim3 gA((BB*NQ)/64, 3);
  hipLaunchKernelGGL(mlp3_kernel, gA, dim3(256), 0, stream,
                     y, x, Wq, bq, Wk, bk, Wv, bv, qbf, kbf, va, vaT);
  hipLaunchKernelGGL(bayes_main_kernel, dim3(BB*(NQ/QT)), dim3(TPB), 0, stream,
                     qbf, kbf, vaT, mask, eps, out, attn, klws);
  hipLaunchKernelGGL(kld_reduce_kernel, dim3(1), dim3(256), 0, stream, klws, kld);
}